// Round 1
// baseline (122.252 us; speedup 1.0000x reference)
//
#include <hip/hip_runtime.h>
#include <math.h>

#define N_SAMPLES 131072
#define HIDDEN    256
#define M_GRID    2048
#define REC       148          // floats per table record
#define U_LO      (-8.0f)
#define DELTA     0.0078125f   // 16 / 2048
#define INV_DELTA 128.0f
#define MT3       16           // m-tile of the layer-3 kernel

// Record layout (148 floats = 37 float4):
//   [0..16]   cw  (knot x positions, cw[0]=-5, cw[16]=5)
//   [17..19]  pad
//   for k in 0..15: base = 20 + 8k:
//     [base+0] ch[k]  [base+1] ch[k+1]  [base+2] dv[k]  [base+3] dv[k+1]
//     [base+4] lam[k] [base+5..7] pad
__device__ float g_H2[HIDDEN * M_GRID];     // 2 MB
__device__ float g_table[M_GRID * REC];     // 1.2 MB
__device__ float g_knots0[REC];

__device__ __forceinline__ float rcpf(float x) { return __builtin_amdgcn_rcpf(x); }

__device__ __forceinline__ float softplusf(float x) {
  return fmaxf(x, 0.0f) + log1pf(expf(-fabsf(x)));
}

// Process one 63-value raw-param column into a record (vectorized stores).
__device__ void process_column(const float* __restrict__ raw, int stride,
                               float* __restrict__ rec) {
  float v[16];
  float cw[17], ch[17], dv[17], lm[16];
  // ---- widths -> cw ----
  float mx = -1e30f;
#pragma unroll
  for (int k = 0; k < 16; k++) { v[k] = raw[k * stride]; mx = fmaxf(mx, v[k]); }
  float s = 0.0f;
#pragma unroll
  for (int k = 0; k < 16; k++) { v[k] = expf(v[k] - mx); s += v[k]; }
  float scl = 0.984f / s;  // (1 - MIN_BIN*K)
  cw[0] = -5.0f;
  float a = 0.0f;
#pragma unroll
  for (int k = 0; k < 16; k++) {
    a += fmaf(v[k], scl, 0.001f);
    cw[k + 1] = fmaf(a, 10.0f, -5.0f);
  }
  cw[16] = 5.0f;
  // ---- heights -> ch ----
  mx = -1e30f;
#pragma unroll
  for (int k = 0; k < 16; k++) { v[k] = raw[(16 + k) * stride]; mx = fmaxf(mx, v[k]); }
  s = 0.0f;
#pragma unroll
  for (int k = 0; k < 16; k++) { v[k] = expf(v[k] - mx); s += v[k]; }
  scl = 0.984f / s;
  ch[0] = -5.0f;
  a = 0.0f;
#pragma unroll
  for (int k = 0; k < 16; k++) {
    a += fmaf(v[k], scl, 0.001f);
    ch[k + 1] = fmaf(a, 10.0f, -5.0f);
  }
  ch[16] = 5.0f;
  // ---- derivatives (boundary = 1) ----
  dv[0] = 1.0f; dv[16] = 1.0f;
#pragma unroll
  for (int j = 0; j < 15; j++) dv[j + 1] = 0.001f + softplusf(raw[(32 + j) * stride]);
  // ---- lambdas ----
#pragma unroll
  for (int k = 0; k < 16; k++) {
    float xx = raw[(47 + k) * stride];
    lm[k] = fmaf(0.95f, 1.0f / (1.0f + expf(-xx)), 0.025f);
  }
  // ---- emit as 37 dwordx4 stores ----
  float4* r4 = (float4*)rec;
  r4[0] = make_float4(cw[0], cw[1], cw[2], cw[3]);
  r4[1] = make_float4(cw[4], cw[5], cw[6], cw[7]);
  r4[2] = make_float4(cw[8], cw[9], cw[10], cw[11]);
  r4[3] = make_float4(cw[12], cw[13], cw[14], cw[15]);
  r4[4] = make_float4(cw[16], 0.0f, 0.0f, 0.0f);
#pragma unroll
  for (int k = 0; k < 16; k++) {
    r4[5 + 2 * k] = make_float4(ch[k], ch[k + 1], dv[k], dv[k + 1]);
    r4[6 + 2 * k] = make_float4(lm[k], 0.0f, 0.0f, 0.0f);
  }
}

// Monotonic linear-rational spline (approx rcp/sqrt; tol 0.099 >> 1ulp).
__device__ __forceinline__ float spline_eval(float z, float xk, float xk1,
                                             float yk, float yk1,
                                             float dk, float dk1, float lam) {
  float xc = fminf(fmaxf(z, -5.0f), 5.0f);
  float wk = xk1 - xk;
  float hk = yk1 - yk;
  float wb = __builtin_amdgcn_sqrtf(dk * rcpf(dk1));
  float wc = fmaf(lam, dk, (1.0f - lam) * wb * dk1) * wk * rcpf(hk);
  float ya = yk;
  float yb = yk + hk;
  float yc = fmaf(lam * wb, yb, (1.0f - lam) * ya) * rcpf(fmaf(lam, wb, 1.0f - lam));
  float th = (xc - xk) * rcpf(wk);
  bool left = th <= lam;
  float num = left ? fmaf(ya, lam - th, wc * yc * th)
                   : fmaf(wc * yc, 1.0f - th, wb * yb * (th - lam));
  float den = left ? fmaf(wc, th, lam - th)
                   : fmaf(wc, 1.0f - th, wb * (th - lam));
  float y = num * rcpf(den);
  bool inside = (z >= -5.0f) && (z <= 5.0f);
  return inside ? y : z;
}

// ---------------- Layer-2 GEMM: H2[o][m] = relu(sum_k W2[o][k]*h_k(u_m) + b2[o])
// h_k(u) = relu(W1[2k]*u + b1[k]) is recomputed in-register from the analytic
// grid (u_m = m*DELTA + U_LO); (W1[2k], b1[k]) are wave-uniform -> scalar loads.
// This removes the Ht LDS tile: per k the wave issues 1 ds_read_b128 instead of
// 2, turning the LDS-pipe-bound loop (~24.6K cyc/CU) into a balanced ~12.3K.
__global__ __launch_bounds__(256) void k_gemm2(const float* __restrict__ W1,
                                               const float* __restrict__ b1,
                                               const float* __restrict__ W2,
                                               const float* __restrict__ b2) {
  __shared__ float Wt[64][68];  // [k][o]
  const int t = threadIdx.x;
  const int m0 = blockIdx.x * 64;
  const int o0 = blockIdx.y * 64;
  const int ty = t >> 4, tx = t & 15;
  float u[4];
#pragma unroll
  for (int j = 0; j < 4; j++) u[j] = fmaf((float)(m0 + tx * 4 + j), DELTA, U_LO);
  float acc[4][4] = {};
  for (int kc = 0; kc < 256; kc += 64) {
    {
      const int o = t >> 2, seg = t & 3;
      const float* src = W2 + (size_t)(o0 + o) * 256 + kc + seg * 16;
#pragma unroll
      for (int q = 0; q < 4; q++) {
        float4 v = *(const float4*)(src + 4 * q);
        int k = seg * 16 + 4 * q;
        Wt[k + 0][o] = v.x; Wt[k + 1][o] = v.y;
        Wt[k + 2][o] = v.z; Wt[k + 3][o] = v.w;
      }
    }
    __syncthreads();
#pragma unroll
    for (int k = 0; k < 64; k++) {
      const float w1v = W1[2 * (kc + k)];   // wave-uniform -> s_load
      const float b1v = b1[kc + k];         // wave-uniform -> s_load
      float4 av = *(const float4*)&Wt[k][ty * 4];
      float bv0 = fmaxf(fmaf(u[0], w1v, b1v), 0.0f);
      float bv1 = fmaxf(fmaf(u[1], w1v, b1v), 0.0f);
      float bv2 = fmaxf(fmaf(u[2], w1v, b1v), 0.0f);
      float bv3 = fmaxf(fmaf(u[3], w1v, b1v), 0.0f);
      acc[0][0] = fmaf(av.x, bv0, acc[0][0]); acc[0][1] = fmaf(av.x, bv1, acc[0][1]);
      acc[0][2] = fmaf(av.x, bv2, acc[0][2]); acc[0][3] = fmaf(av.x, bv3, acc[0][3]);
      acc[1][0] = fmaf(av.y, bv0, acc[1][0]); acc[1][1] = fmaf(av.y, bv1, acc[1][1]);
      acc[1][2] = fmaf(av.y, bv2, acc[1][2]); acc[1][3] = fmaf(av.y, bv3, acc[1][3]);
      acc[2][0] = fmaf(av.z, bv0, acc[2][0]); acc[2][1] = fmaf(av.z, bv1, acc[2][1]);
      acc[2][2] = fmaf(av.z, bv2, acc[2][2]); acc[2][3] = fmaf(av.z, bv3, acc[2][3]);
      acc[3][0] = fmaf(av.w, bv0, acc[3][0]); acc[3][1] = fmaf(av.w, bv1, acc[3][1]);
      acc[3][2] = fmaf(av.w, bv2, acc[3][2]); acc[3][3] = fmaf(av.w, bv3, acc[3][3]);
    }
    __syncthreads();
  }
#pragma unroll
  for (int ii = 0; ii < 4; ii++) {
    const int o = o0 + ty * 4 + ii;
    const float bias = b2[o];
    float4 r;
    r.x = fmaxf(acc[ii][0] + bias, 0.0f);
    r.y = fmaxf(acc[ii][1] + bias, 0.0f);
    r.z = fmaxf(acc[ii][2] + bias, 0.0f);
    r.w = fmaxf(acc[ii][3] + bias, 0.0f);
    *(float4*)&g_H2[(size_t)o * M_GRID + m0 + tx * 4] = r;
  }
}

// ---------------- Layer-3 GEMM (odd rows of W3) + param processing -> g_table
// Restructured: m-tile 16 over 128 blocks (was 64 over 32 -> 4x CU coverage).
// W3^T and the H2 slice are staged ONCE (no per-chunk restage), and the K=256
// reduction is split across the 4 waves (64 each) with an LDS partial-sum
// combine, so the per-CU LDS-read demand drops ~4x.
__global__ __launch_bounds__(256) void k_gemm3proc(const float* __restrict__ W3,
                                                   const float* __restrict__ b3) {
  __shared__ float Wt[256][66];     // [k][p]  67.6 KB
  __shared__ float Ht[256][18];     // [k][m'] 18.4 KB
  __shared__ float red[3][64][20];  // wave partials, 15.4 KB (b128-aligned rows)
  __shared__ float raws[64][18];    // [p][m']  4.6 KB
  const int t = threadIdx.x;
  const int m0 = blockIdx.x * MT3;
  // ---- stage W3-odd rows transposed, all K ----
  {
    const int p = t >> 2, seg = t & 3;
    const int row = (p < 63) ? (2 * p + 1) : 1;
    const float* src = W3 + (size_t)row * 256 + seg * 16;
#pragma unroll
    for (int kc = 0; kc < 256; kc += 64) {
#pragma unroll
      for (int q = 0; q < 4; q++) {
        float4 v = *(const float4*)(src + kc + 4 * q);
        int k = kc + seg * 16 + 4 * q;
        Wt[k + 0][p] = v.x; Wt[k + 1][p] = v.y;
        Wt[k + 2][p] = v.z; Wt[k + 3][p] = v.w;
      }
    }
  }
  // ---- stage H2[k][m0..m0+16), thread t handles k = t ----
  {
    const float* src = g_H2 + (size_t)t * M_GRID + m0;
#pragma unroll
    for (int q = 0; q < 4; q++) {
      float4 v = *(const float4*)(src + 4 * q);
      *(float4*)&Ht[t][4 * q] = v;
    }
  }
  __syncthreads();
  // ---- FMA phase: wave w sums K-slice [64w, 64w+64) ----
  const int w = t >> 6, lane = t & 63;
  const int tp = lane >> 2, tm = lane & 3;
  const int kbase = w * 64;
  float acc[4][4] = {};
#pragma unroll
  for (int k = 0; k < 64; k++) {
    float4 av = *(const float4*)&Wt[kbase + k][tp * 4];
    float4 bv = *(const float4*)&Ht[kbase + k][tm * 4];
    acc[0][0] = fmaf(av.x, bv.x, acc[0][0]); acc[0][1] = fmaf(av.x, bv.y, acc[0][1]);
    acc[0][2] = fmaf(av.x, bv.z, acc[0][2]); acc[0][3] = fmaf(av.x, bv.w, acc[0][3]);
    acc[1][0] = fmaf(av.y, bv.x, acc[1][0]); acc[1][1] = fmaf(av.y, bv.y, acc[1][1]);
    acc[1][2] = fmaf(av.y, bv.z, acc[1][2]); acc[1][3] = fmaf(av.y, bv.w, acc[1][3]);
    acc[2][0] = fmaf(av.z, bv.x, acc[2][0]); acc[2][1] = fmaf(av.z, bv.y, acc[2][1]);
    acc[2][2] = fmaf(av.z, bv.z, acc[2][2]); acc[2][3] = fmaf(av.z, bv.w, acc[2][3]);
    acc[3][0] = fmaf(av.w, bv.x, acc[3][0]); acc[3][1] = fmaf(av.w, bv.y, acc[3][1]);
    acc[3][2] = fmaf(av.w, bv.z, acc[3][2]); acc[3][3] = fmaf(av.w, bv.w, acc[3][3]);
  }
  if (w > 0) {
#pragma unroll
    for (int i = 0; i < 4; i++)
      *(float4*)&red[w - 1][lane][4 * i] =
          make_float4(acc[i][0], acc[i][1], acc[i][2], acc[i][3]);
  }
  __syncthreads();
  if (w == 0) {
#pragma unroll
    for (int i = 0; i < 4; i++) {
      float4 r0 = *(const float4*)&red[0][lane][4 * i];
      float4 r1 = *(const float4*)&red[1][lane][4 * i];
      float4 r2 = *(const float4*)&red[2][lane][4 * i];
      const int p = tp * 4 + i;
      const int bi = (p < 63) ? (2 * p + 1) : 1;
      const float bias = b3[bi];
      raws[p][tm * 4 + 0] = acc[i][0] + r0.x + r1.x + r2.x + bias;
      raws[p][tm * 4 + 1] = acc[i][1] + r0.y + r1.y + r2.y + bias;
      raws[p][tm * 4 + 2] = acc[i][2] + r0.z + r1.z + r2.z + bias;
      raws[p][tm * 4 + 3] = acc[i][3] + r0.w + r1.w + r2.w + bias;
    }
  }
  __syncthreads();
  if (t < MT3) process_column(&raws[0][t], 18, g_table + (size_t)(m0 + t) * REC);
  if (t == 64 && blockIdx.x == 0) process_column(b3, 2, g_knots0);  // dim-0 constant knots
}

// ---------------- Main flow kernel: 4 steps per sample
__global__ __launch_bounds__(256) void k_main(const float* __restrict__ x,
                                              float* __restrict__ out) {
  __shared__ float kn0[REC];
  for (int j = threadIdx.x; j < REC; j += 256) kn0[j] = g_knots0[j];
  __syncthreads();
  const int i = blockIdx.x * 256 + threadIdx.x;
  const float2 xv = ((const float2*)x)[i];
  float z0 = xv.x, z1 = xv.y;
  ((float2*)out)[i] = xv;  // step 0 = input
  for (int t = 0; t < 4; t++) {
    // ---- dim 1: table lookup keyed by u = current z0 ----
    float tt = (z0 - U_LO) * INV_DELTA;
    int i0 = (int)floorf(tt);
    i0 = min(max(i0, 0), M_GRID - 2);
    float f = fminf(fmaxf(tt - (float)i0, 0.0f), 1.0f);
    const float* r0 = g_table + (size_t)i0 * REC;
    const float* r1 = r0 + REC;
    float cwv[17];
#pragma unroll
    for (int q = 0; q < 4; q++) {
      float4 a = *(const float4*)(r0 + 4 * q);
      float4 b = *(const float4*)(r1 + 4 * q);
      cwv[4 * q + 0] = fmaf(f, b.x - a.x, a.x);
      cwv[4 * q + 1] = fmaf(f, b.y - a.y, a.y);
      cwv[4 * q + 2] = fmaf(f, b.z - a.z, a.z);
      cwv[4 * q + 3] = fmaf(f, b.w - a.w, a.w);
    }
    cwv[16] = 5.0f;  // exact in every record
    float xc1 = fminf(fmaxf(z1, -5.0f), 5.0f);
    int k1 = -1;
    float xk = cwv[0], xk1 = cwv[16];
    bool seen = false;
#pragma unroll
    for (int j = 0; j < 16; j++) {
      bool c = xc1 >= cwv[j];
      k1 += c ? 1 : 0;
      xk = c ? cwv[j] : xk;
      bool ff = (!c) && (!seen);
      xk1 = ff ? cwv[j] : xk1;
      seen = seen || (!c);
    }
    const float* s0 = r0 + 20 + 8 * k1;
    const float* s1 = s0 + REC;
    float4 pa = *(const float4*)s0;
    float4 pb = *(const float4*)s1;
    float la = s0[4], lb = s1[4];
    float yk  = fmaf(f, pb.x - pa.x, pa.x);
    float yk1 = fmaf(f, pb.y - pa.y, pa.y);
    float dk  = fmaf(f, pb.z - pa.z, pa.z);
    float dk1 = fmaf(f, pb.w - pa.w, pa.w);
    float lam = fmaf(f, lb - la, la);
    float z1n = spline_eval(z1, xk, xk1, yk, yk1, dk, dk1, lam);
    // ---- dim 0: constant knots from LDS ----
    float xc0 = fminf(fmaxf(z0, -5.0f), 5.0f);
    int k0 = -1;
    float xk0 = kn0[0], xk01 = kn0[16];
    bool seen0 = false;
#pragma unroll
    for (int j = 0; j < 16; j++) {
      float cj = kn0[j];
      bool c = xc0 >= cj;
      k0 += c ? 1 : 0;
      xk0 = c ? cj : xk0;
      bool ff = (!c) && (!seen0);
      xk01 = ff ? cj : xk01;
      seen0 = seen0 || (!c);
    }
    const int sb = 20 + 8 * k0;
    float z0n = spline_eval(z0, xk0, xk01, kn0[sb], kn0[sb + 1],
                            kn0[sb + 2], kn0[sb + 3], kn0[sb + 4]);
    z0 = z0n; z1 = z1n;
    ((float2*)(out + (size_t)(t + 1) * (N_SAMPLES * 2)))[i] = make_float2(z0, z1);
  }
}

extern "C" void kernel_launch(void* const* d_in, const int* in_sizes, int n_in,
                              void* d_out, int out_size, void* d_ws, size_t ws_size,
                              hipStream_t stream) {
  const float* x  = (const float*)d_in[0];
  const float* W1 = (const float*)d_in[1];
  const float* b1 = (const float*)d_in[2];
  const float* W2 = (const float*)d_in[3];
  const float* b2 = (const float*)d_in[4];
  const float* W3 = (const float*)d_in[5];
  const float* b3 = (const float*)d_in[6];
  float* out = (float*)d_out;
  hipLaunchKernelGGL(k_gemm2, dim3(M_GRID / 64, 4), dim3(256), 0, stream, W1, b1, W2, b2);
  hipLaunchKernelGGL(k_gemm3proc, dim3(M_GRID / MT3), dim3(256), 0, stream, W3, b3);
  hipLaunchKernelGGL(k_main, dim3(N_SAMPLES / 256), dim3(256), 0, stream, x, out);
}

// Round 2
// 105.671 us; speedup vs baseline: 1.1569x; 1.1569x over previous
//
#include <hip/hip_runtime.h>
#include <math.h>

#define N_SAMPLES 131072
#define HIDDEN    256
#define M_GRID    2048
#define REC       160          // floats per table record (640B, line-aligned)
#define U_LO      (-8.0f)
#define DELTA     0.0078125f   // 16 / 2048
#define INV_DELTA 128.0f
#define MT3       16           // m-tile of the layer-3 kernel

// Record layout (first 148 floats used, padded to 160):
//   [0..16]   cw  (knot x positions, cw[0]=-5, cw[16]=5)
//   [17..19]  pad
//   for k in 0..15: base = 20 + 8k:
//     [base+0] ch[k]  [base+1] ch[k+1]  [base+2] dv[k]  [base+3] dv[k+1]
//     [base+4] lam[k] [base+5..7] pad
__device__ float g_H2T[M_GRID * HIDDEN];    // 2 MB, TRANSPOSED: [m][k]
__device__ float g_table[M_GRID * REC];     // 1.31 MB
__device__ float g_knots0[REC];

__device__ __forceinline__ float rcpf(float x) { return __builtin_amdgcn_rcpf(x); }

__device__ __forceinline__ float softplusf(float x) {
  return fmaxf(x, 0.0f) + log1pf(expf(-fabsf(x)));
}

// Process one 63-value raw-param column into a record (vectorized stores).
__device__ void process_column(const float* __restrict__ raw, int stride,
                               float* __restrict__ rec) {
  float v[16];
  float cw[17], ch[17], dv[17], lm[16];
  // ---- widths -> cw ----
  float mx = -1e30f;
#pragma unroll
  for (int k = 0; k < 16; k++) { v[k] = raw[k * stride]; mx = fmaxf(mx, v[k]); }
  float s = 0.0f;
#pragma unroll
  for (int k = 0; k < 16; k++) { v[k] = expf(v[k] - mx); s += v[k]; }
  float scl = 0.984f / s;  // (1 - MIN_BIN*K)
  cw[0] = -5.0f;
  float a = 0.0f;
#pragma unroll
  for (int k = 0; k < 16; k++) {
    a += fmaf(v[k], scl, 0.001f);
    cw[k + 1] = fmaf(a, 10.0f, -5.0f);
  }
  cw[16] = 5.0f;
  // ---- heights -> ch ----
  mx = -1e30f;
#pragma unroll
  for (int k = 0; k < 16; k++) { v[k] = raw[(16 + k) * stride]; mx = fmaxf(mx, v[k]); }
  s = 0.0f;
#pragma unroll
  for (int k = 0; k < 16; k++) { v[k] = expf(v[k] - mx); s += v[k]; }
  scl = 0.984f / s;
  ch[0] = -5.0f;
  a = 0.0f;
#pragma unroll
  for (int k = 0; k < 16; k++) {
    a += fmaf(v[k], scl, 0.001f);
    ch[k + 1] = fmaf(a, 10.0f, -5.0f);
  }
  ch[16] = 5.0f;
  // ---- derivatives (boundary = 1) ----
  dv[0] = 1.0f; dv[16] = 1.0f;
#pragma unroll
  for (int j = 0; j < 15; j++) dv[j + 1] = 0.001f + softplusf(raw[(32 + j) * stride]);
  // ---- lambdas ----
#pragma unroll
  for (int k = 0; k < 16; k++) {
    float xx = raw[(47 + k) * stride];
    lm[k] = fmaf(0.95f, 1.0f / (1.0f + expf(-xx)), 0.025f);
  }
  // ---- emit as dwordx4 stores ----
  float4* r4 = (float4*)rec;
  r4[0] = make_float4(cw[0], cw[1], cw[2], cw[3]);
  r4[1] = make_float4(cw[4], cw[5], cw[6], cw[7]);
  r4[2] = make_float4(cw[8], cw[9], cw[10], cw[11]);
  r4[3] = make_float4(cw[12], cw[13], cw[14], cw[15]);
  r4[4] = make_float4(cw[16], 0.0f, 0.0f, 0.0f);
#pragma unroll
  for (int k = 0; k < 16; k++) {
    r4[5 + 2 * k] = make_float4(ch[k], ch[k + 1], dv[k], dv[k + 1]);
    r4[6 + 2 * k] = make_float4(lm[k], 0.0f, 0.0f, 0.0f);
  }
}

// Monotonic linear-rational spline (approx rcp/sqrt; tol 0.099 >> 1ulp).
__device__ __forceinline__ float spline_eval(float z, float xk, float xk1,
                                             float yk, float yk1,
                                             float dk, float dk1, float lam) {
  float xc = fminf(fmaxf(z, -5.0f), 5.0f);
  float wk = xk1 - xk;
  float hk = yk1 - yk;
  float wb = __builtin_amdgcn_sqrtf(dk * rcpf(dk1));
  float wc = fmaf(lam, dk, (1.0f - lam) * wb * dk1) * wk * rcpf(hk);
  float ya = yk;
  float yb = yk + hk;
  float yc = fmaf(lam * wb, yb, (1.0f - lam) * ya) * rcpf(fmaf(lam, wb, 1.0f - lam));
  float th = (xc - xk) * rcpf(wk);
  bool left = th <= lam;
  float num = left ? fmaf(ya, lam - th, wc * yc * th)
                   : fmaf(wc * yc, 1.0f - th, wb * yb * (th - lam));
  float den = left ? fmaf(wc, th, lam - th)
                   : fmaf(wc, 1.0f - th, wb * (th - lam));
  float y = num * rcpf(den);
  bool inside = (z >= -5.0f) && (z <= 5.0f);
  return inside ? y : z;
}

// ---------------- Layer-2 GEMM: H2T[m][o] = relu(sum_k W2[o][k]*h_k(u_m) + b2[o])
// Tile 64o x 32m, grid (64,4) = 256 blocks (full CU coverage).
// Full-K staged once; the 4 waves split K (64 each, 32 acc/lane) -> LDS k-loop
// demand drops 24.6K -> 9.2K cyc/CU. Partial sums reduced through the Ht
// buffer (aliased; dead after the k-loop). Output written TRANSPOSED [m][k]
// so the layer-3 kernel's m-slice stage is a contiguous coalesced read.
__global__ __launch_bounds__(256) void k_gemm2(const float* __restrict__ W1,
                                               const float* __restrict__ b1,
                                               const float* __restrict__ W2,
                                               const float* __restrict__ b2) {
  __shared__ float sW[256 * 67];  // W2^T [k][o], stride 67 (2-way = free)
  __shared__ float sH[256 * 36];  // h [k][m], stride 36; aliased as red buffer
  const int t = threadIdx.x;
  const int m0 = blockIdx.x * 32;
  const int o0 = blockIdx.y * 64;
  // ---- stage W2^T: k = 64c + 16seg + 4q + j keeps banks 2-way (free) ----
  {
    const int ol = t >> 2, seg = t & 3;
    const float* src = W2 + (size_t)(o0 + ol) * 256 + 16 * seg;
#pragma unroll
    for (int c = 0; c < 4; c++) {
#pragma unroll
      for (int q = 0; q < 4; q++) {
        float4 v = *(const float4*)(src + 64 * c + 4 * q);
        const int k = 64 * c + 16 * seg + 4 * q;
        sW[(k + 0) * 67 + ol] = v.x;
        sW[(k + 1) * 67 + ol] = v.y;
        sW[(k + 2) * 67 + ol] = v.z;
        sW[(k + 3) * 67 + ol] = v.w;
      }
    }
  }
  // ---- analytic h row k = t (no W1/b1 LDS tile; per-thread loads) ----
  {
    const float w1v = W1[2 * t];
    const float b1v = b1[t];
#pragma unroll
    for (int q = 0; q < 8; q++) {
      float4 h;
      float u0 = fmaf((float)(m0 + 4 * q + 0), DELTA, U_LO);
      float u1 = fmaf((float)(m0 + 4 * q + 1), DELTA, U_LO);
      float u2 = fmaf((float)(m0 + 4 * q + 2), DELTA, U_LO);
      float u3 = fmaf((float)(m0 + 4 * q + 3), DELTA, U_LO);
      h.x = fmaxf(fmaf(u0, w1v, b1v), 0.0f);
      h.y = fmaxf(fmaf(u1, w1v, b1v), 0.0f);
      h.z = fmaxf(fmaf(u2, w1v, b1v), 0.0f);
      h.w = fmaxf(fmaf(u3, w1v, b1v), 0.0f);
      *(float4*)&sH[t * 36 + 4 * q] = h;
    }
  }
  __syncthreads();
  // ---- wave-split-K FMA phase: wave w owns k in [64w, 64w+64) ----
  const int w = t >> 6, lane = t & 63;
  const int tp = lane >> 2, tm = lane & 3;  // o = o0+4tp+i, m = m0+8tm+j
  float acc[4][8] = {};
  const int kb = w * 64;
#pragma unroll 8
  for (int kk = 0; kk < 64; kk++) {
    const int k = kb + kk;
    float4 av = *(const float4*)&sW[k * 67 + 4 * tp];
    float4 b0 = *(const float4*)&sH[k * 36 + 8 * tm];
    float4 b1v = *(const float4*)&sH[k * 36 + 8 * tm + 4];
#pragma unroll
    for (int i = 0; i < 4; i++) {
      const float a = (i == 0) ? av.x : (i == 1) ? av.y : (i == 2) ? av.z : av.w;
      acc[i][0] = fmaf(a, b0.x, acc[i][0]);
      acc[i][1] = fmaf(a, b0.y, acc[i][1]);
      acc[i][2] = fmaf(a, b0.z, acc[i][2]);
      acc[i][3] = fmaf(a, b0.w, acc[i][3]);
      acc[i][4] = fmaf(a, b1v.x, acc[i][4]);
      acc[i][5] = fmaf(a, b1v.y, acc[i][5]);
      acc[i][6] = fmaf(a, b1v.z, acc[i][6]);
      acc[i][7] = fmaf(a, b1v.w, acc[i][7]);
    }
  }
  __syncthreads();  // everyone done reading sH; safe to alias as red buffer
  if (w > 0) {
#pragma unroll
    for (int i = 0; i < 4; i++) {
      *(float4*)&sH[((w - 1) * 64 + lane) * 36 + 8 * i] =
          make_float4(acc[i][0], acc[i][1], acc[i][2], acc[i][3]);
      *(float4*)&sH[((w - 1) * 64 + lane) * 36 + 8 * i + 4] =
          make_float4(acc[i][4], acc[i][5], acc[i][6], acc[i][7]);
    }
  }
  __syncthreads();
  if (w == 0) {
#pragma unroll
    for (int v = 0; v < 3; v++) {
#pragma unroll
      for (int i = 0; i < 4; i++) {
        float4 r0 = *(const float4*)&sH[(v * 64 + lane) * 36 + 8 * i];
        float4 r1 = *(const float4*)&sH[(v * 64 + lane) * 36 + 8 * i + 4];
        acc[i][0] += r0.x; acc[i][1] += r0.y; acc[i][2] += r0.z; acc[i][3] += r0.w;
        acc[i][4] += r1.x; acc[i][5] += r1.y; acc[i][6] += r1.z; acc[i][7] += r1.w;
      }
    }
    float4 bb = *(const float4*)&b2[o0 + 4 * tp];
#pragma unroll
    for (int j = 0; j < 8; j++) {
      float4 r;
      r.x = fmaxf(acc[0][j] + bb.x, 0.0f);
      r.y = fmaxf(acc[1][j] + bb.y, 0.0f);
      r.z = fmaxf(acc[2][j] + bb.z, 0.0f);
      r.w = fmaxf(acc[3][j] + bb.w, 0.0f);
      *(float4*)&g_H2T[(size_t)(m0 + 8 * tm + j) * 256 + o0 + 4 * tp] = r;
    }
  }
}

// ---------------- Layer-3 GEMM (odd rows of W3) + param processing -> g_table
// Tile 64p x 16m, grid 128 blocks, wave-split-K (16 acc/lane).
// k-loop: per wave 64k x 2 ds_read_b128 -> ~6.1K cyc/CU (vs 24.6K round-0).
__global__ __launch_bounds__(256) void k_gemm3proc(const float* __restrict__ W3,
                                                   const float* __restrict__ b3) {
  __shared__ float sW[256 * 67];   // W3odd^T [k][p]
  __shared__ float sH[256 * 20];   // H2 slice [k][m']; aliased as red buffer
  __shared__ float raws[64 * 20];  // [p][m']
  const int t = threadIdx.x;
  const int m0 = blockIdx.x * MT3;
  // ---- stage W3odd^T (same conflict-free k decomposition) ----
  {
    const int ol = t >> 2, seg = t & 3;
    const int row = (ol < 63) ? (2 * ol + 1) : 1;
    const float* src = W3 + (size_t)row * 256 + 16 * seg;
#pragma unroll
    for (int c = 0; c < 4; c++) {
#pragma unroll
      for (int q = 0; q < 4; q++) {
        float4 v = *(const float4*)(src + 64 * c + 4 * q);
        const int k = 64 * c + 16 * seg + 4 * q;
        sW[(k + 0) * 67 + ol] = v.x;
        sW[(k + 1) * 67 + ol] = v.y;
        sW[(k + 2) * 67 + ol] = v.z;
        sW[(k + 3) * 67 + ol] = v.w;
      }
    }
  }
  // ---- stage H2T slice (contiguous rows -> coalesced) into [k][m'] ----
  {
    const int j = t & 15, c = t >> 4;  // m-row j, k-chunk c
    const float* src = g_H2T + (size_t)(m0 + j) * 256 + 16 * c;
#pragma unroll
    for (int q = 0; q < 4; q++) {
      float4 v = *(const float4*)(src + 4 * q);
      const int k = 16 * c + 4 * q;
      sH[(k + 0) * 20 + j] = v.x;
      sH[(k + 1) * 20 + j] = v.y;
      sH[(k + 2) * 20 + j] = v.z;
      sH[(k + 3) * 20 + j] = v.w;
    }
  }
  __syncthreads();
  // ---- wave-split-K FMA phase ----
  const int w = t >> 6, lane = t & 63;
  const int tp = lane >> 2, tm = lane & 3;  // p = 4tp+i, m = 4tm+j
  float acc[4][4] = {};
  const int kb = w * 64;
#pragma unroll 8
  for (int kk = 0; kk < 64; kk++) {
    const int k = kb + kk;
    float4 av = *(const float4*)&sW[k * 67 + 4 * tp];
    float4 bv = *(const float4*)&sH[k * 20 + 4 * tm];
    acc[0][0] = fmaf(av.x, bv.x, acc[0][0]); acc[0][1] = fmaf(av.x, bv.y, acc[0][1]);
    acc[0][2] = fmaf(av.x, bv.z, acc[0][2]); acc[0][3] = fmaf(av.x, bv.w, acc[0][3]);
    acc[1][0] = fmaf(av.y, bv.x, acc[1][0]); acc[1][1] = fmaf(av.y, bv.y, acc[1][1]);
    acc[1][2] = fmaf(av.y, bv.z, acc[1][2]); acc[1][3] = fmaf(av.y, bv.w, acc[1][3]);
    acc[2][0] = fmaf(av.z, bv.x, acc[2][0]); acc[2][1] = fmaf(av.z, bv.y, acc[2][1]);
    acc[2][2] = fmaf(av.z, bv.z, acc[2][2]); acc[2][3] = fmaf(av.z, bv.w, acc[2][3]);
    acc[3][0] = fmaf(av.w, bv.x, acc[3][0]); acc[3][1] = fmaf(av.w, bv.y, acc[3][1]);
    acc[3][2] = fmaf(av.w, bv.z, acc[3][2]); acc[3][3] = fmaf(av.w, bv.w, acc[3][3]);
  }
  __syncthreads();  // sH dead; alias as red buffer
  if (w > 0) {
#pragma unroll
    for (int i = 0; i < 4; i++)
      *(float4*)&sH[((w - 1) * 64 + lane) * 20 + 4 * i] =
          make_float4(acc[i][0], acc[i][1], acc[i][2], acc[i][3]);
  }
  __syncthreads();
  if (w == 0) {
#pragma unroll
    for (int v = 0; v < 3; v++) {
#pragma unroll
      for (int i = 0; i < 4; i++) {
        float4 r = *(const float4*)&sH[(v * 64 + lane) * 20 + 4 * i];
        acc[i][0] += r.x; acc[i][1] += r.y; acc[i][2] += r.z; acc[i][3] += r.w;
      }
    }
#pragma unroll
    for (int i = 0; i < 4; i++) {
      const int p = 4 * tp + i;
      const int bi = (p < 63) ? (2 * p + 1) : 1;
      const float bias = b3[bi];
      *(float4*)&raws[p * 20 + 4 * tm] =
          make_float4(acc[i][0] + bias, acc[i][1] + bias,
                      acc[i][2] + bias, acc[i][3] + bias);
    }
  }
  __syncthreads();
  if (t < MT3) process_column(&raws[t], 20, g_table + (size_t)(m0 + t) * REC);
  if (t == 64 && blockIdx.x == 0) process_column(b3, 2, g_knots0);  // dim-0 constant knots
}

// ---------------- Main flow kernel: 4 steps per sample
__global__ __launch_bounds__(256) void k_main(const float* __restrict__ x,
                                              float* __restrict__ out) {
  __shared__ float kn0[REC];
  for (int j = threadIdx.x; j < REC; j += 256) kn0[j] = g_knots0[j];
  __syncthreads();
  const int i = blockIdx.x * 256 + threadIdx.x;
  const float2 xv = ((const float2*)x)[i];
  float z0 = xv.x, z1 = xv.y;
  ((float2*)out)[i] = xv;  // step 0 = input
  for (int t = 0; t < 4; t++) {
    // ---- dim 1: table lookup keyed by u = current z0 ----
    float tt = (z0 - U_LO) * INV_DELTA;
    int i0 = (int)floorf(tt);
    i0 = min(max(i0, 0), M_GRID - 2);
    float f = fminf(fmaxf(tt - (float)i0, 0.0f), 1.0f);
    const float* r0 = g_table + (size_t)i0 * REC;
    const float* r1 = r0 + REC;
    float cwv[17];
#pragma unroll
    for (int q = 0; q < 4; q++) {
      float4 a = *(const float4*)(r0 + 4 * q);
      float4 b = *(const float4*)(r1 + 4 * q);
      cwv[4 * q + 0] = fmaf(f, b.x - a.x, a.x);
      cwv[4 * q + 1] = fmaf(f, b.y - a.y, a.y);
      cwv[4 * q + 2] = fmaf(f, b.z - a.z, a.z);
      cwv[4 * q + 3] = fmaf(f, b.w - a.w, a.w);
    }
    cwv[16] = 5.0f;  // exact in every record
    float xc1 = fminf(fmaxf(z1, -5.0f), 5.0f);
    int k1 = -1;
    float xk = cwv[0], xk1 = cwv[16];
    bool seen = false;
#pragma unroll
    for (int j = 0; j < 16; j++) {
      bool c = xc1 >= cwv[j];
      k1 += c ? 1 : 0;
      xk = c ? cwv[j] : xk;
      bool ff = (!c) && (!seen);
      xk1 = ff ? cwv[j] : xk1;
      seen = seen || (!c);
    }
    const float* s0 = r0 + 20 + 8 * k1;
    const float* s1 = s0 + REC;
    float4 pa = *(const float4*)s0;
    float4 pb = *(const float4*)s1;
    float la = s0[4], lb = s1[4];
    float yk  = fmaf(f, pb.x - pa.x, pa.x);
    float yk1 = fmaf(f, pb.y - pa.y, pa.y);
    float dk  = fmaf(f, pb.z - pa.z, pa.z);
    float dk1 = fmaf(f, pb.w - pa.w, pa.w);
    float lam = fmaf(f, lb - la, la);
    float z1n = spline_eval(z1, xk, xk1, yk, yk1, dk, dk1, lam);
    // ---- dim 0: constant knots from LDS ----
    float xc0 = fminf(fmaxf(z0, -5.0f), 5.0f);
    int k0 = -1;
    float xk0 = kn0[0], xk01 = kn0[16];
    bool seen0 = false;
#pragma unroll
    for (int j = 0; j < 16; j++) {
      float cj = kn0[j];
      bool c = xc0 >= cj;
      k0 += c ? 1 : 0;
      xk0 = c ? cj : xk0;
      bool ff = (!c) && (!seen0);
      xk01 = ff ? cj : xk01;
      seen0 = seen0 || (!c);
    }
    const int sb = 20 + 8 * k0;
    float z0n = spline_eval(z0, xk0, xk01, kn0[sb], kn0[sb + 1],
                            kn0[sb + 2], kn0[sb + 3], kn0[sb + 4]);
    z0 = z0n; z1 = z1n;
    ((float2*)(out + (size_t)(t + 1) * (N_SAMPLES * 2)))[i] = make_float2(z0, z1);
  }
}

extern "C" void kernel_launch(void* const* d_in, const int* in_sizes, int n_in,
                              void* d_out, int out_size, void* d_ws, size_t ws_size,
                              hipStream_t stream) {
  const float* x  = (const float*)d_in[0];
  const float* W1 = (const float*)d_in[1];
  const float* b1 = (const float*)d_in[2];
  const float* W2 = (const float*)d_in[3];
  const float* b2 = (const float*)d_in[4];
  const float* W3 = (const float*)d_in[5];
  const float* b3 = (const float*)d_in[6];
  float* out = (float*)d_out;
  hipLaunchKernelGGL(k_gemm2, dim3(M_GRID / 32, 4), dim3(256), 0, stream, W1, b1, W2, b2);
  hipLaunchKernelGGL(k_gemm3proc, dim3(M_GRID / MT3), dim3(256), 0, stream, W3, b3);
  hipLaunchKernelGGL(k_main, dim3(N_SAMPLES / 256), dim3(256), 0, stream, x, out);
}

// Round 3
// 104.081 us; speedup vs baseline: 1.1746x; 1.0153x over previous
//
#include <hip/hip_runtime.h>
#include <hip/hip_fp16.h>
#include <math.h>

#define N_SAMPLES 131072
#define HIDDEN    256
#define M_GRID    2048
#define REC       144          // floats per table record (576B = 9 cache lines)
#define U_LO      (-8.0f)
#define DELTA     0.0078125f   // 16 / 2048
#define INV_DELTA 128.0f
#define MT3       16           // m-tile of the layer-3 kernel

// Record layout (144 floats / 576 B):
//   bytes   0..31 : 16 fp16 knots cw[0..15]  (search-only; cw[16]=5.0 implicit)
//   bytes  32..63 : pad
//   bytes 64+32k  : float8 bin chunk k: {ch[k], ch[k+1], dv[k], dv[k+1],
//                                        lam[k], cw[k], cw[k+1], pad}
//   (xk/xk1 duplicated in fp32 inside the chunk -> eval precision unchanged;
//    fp16 knots only pick the bin; continuity bounds misassignment error)
__device__ __attribute__((aligned(16))) float g_H2T[M_GRID * HIDDEN];  // [m][k], 2 MB
__device__ __attribute__((aligned(16))) float g_table[M_GRID * REC];   // 1.18 MB
__device__ __attribute__((aligned(16))) float g_knots0[REC];

__device__ __forceinline__ float rcpf(float x) { return __builtin_amdgcn_rcpf(x); }

__device__ __forceinline__ float softplusf(float x) {
  return fmaxf(x, 0.0f) + log1pf(expf(-fabsf(x)));
}

__device__ __forceinline__ void unpack8(uint4 u, float* f) {
  float2 t;
  t = __half22float2(*(__half2*)&u.x); f[0] = t.x; f[1] = t.y;
  t = __half22float2(*(__half2*)&u.y); f[2] = t.x; f[3] = t.y;
  t = __half22float2(*(__half2*)&u.z); f[4] = t.x; f[5] = t.y;
  t = __half22float2(*(__half2*)&u.w); f[6] = t.x; f[7] = t.y;
}

// Process one 63-value raw-param column into a record (new 576B format).
__device__ void process_column(const float* __restrict__ raw, int stride,
                               float* __restrict__ rec) {
  float v[16];
  float cw[17], ch[17], dv[17], lm[16];
  // ---- widths -> cw ----
  float mx = -1e30f;
#pragma unroll
  for (int k = 0; k < 16; k++) { v[k] = raw[k * stride]; mx = fmaxf(mx, v[k]); }
  float s = 0.0f;
#pragma unroll
  for (int k = 0; k < 16; k++) { v[k] = expf(v[k] - mx); s += v[k]; }
  float scl = 0.984f / s;  // (1 - MIN_BIN*K)
  cw[0] = -5.0f;
  float a = 0.0f;
#pragma unroll
  for (int k = 0; k < 16; k++) {
    a += fmaf(v[k], scl, 0.001f);
    cw[k + 1] = fmaf(a, 10.0f, -5.0f);
  }
  cw[16] = 5.0f;
  // ---- heights -> ch ----
  mx = -1e30f;
#pragma unroll
  for (int k = 0; k < 16; k++) { v[k] = raw[(16 + k) * stride]; mx = fmaxf(mx, v[k]); }
  s = 0.0f;
#pragma unroll
  for (int k = 0; k < 16; k++) { v[k] = expf(v[k] - mx); s += v[k]; }
  scl = 0.984f / s;
  ch[0] = -5.0f;
  a = 0.0f;
#pragma unroll
  for (int k = 0; k < 16; k++) {
    a += fmaf(v[k], scl, 0.001f);
    ch[k + 1] = fmaf(a, 10.0f, -5.0f);
  }
  ch[16] = 5.0f;
  // ---- derivatives (boundary = 1) ----
  dv[0] = 1.0f; dv[16] = 1.0f;
#pragma unroll
  for (int j = 0; j < 15; j++) dv[j + 1] = 0.001f + softplusf(raw[(32 + j) * stride]);
  // ---- lambdas ----
#pragma unroll
  for (int k = 0; k < 16; k++) {
    float xx = raw[(47 + k) * stride];
    lm[k] = fmaf(0.95f, 1.0f / (1.0f + expf(-xx)), 0.025f);
  }
  // ---- emit: fp16 knot row + fp32 bin chunks ----
  unsigned int kn[8];
#pragma unroll
  for (int q = 0; q < 8; q++) {
    __half2 h2 = __floats2half2_rn(cw[2 * q], cw[2 * q + 1]);
    kn[q] = *(unsigned int*)&h2;
  }
  uint4* u4 = (uint4*)rec;
  u4[0] = make_uint4(kn[0], kn[1], kn[2], kn[3]);
  u4[1] = make_uint4(kn[4], kn[5], kn[6], kn[7]);
  float4* r4 = (float4*)rec;
  r4[2] = make_float4(0.0f, 0.0f, 0.0f, 0.0f);
  r4[3] = make_float4(0.0f, 0.0f, 0.0f, 0.0f);
#pragma unroll
  for (int k = 0; k < 16; k++) {
    r4[4 + 2 * k]     = make_float4(ch[k], ch[k + 1], dv[k], dv[k + 1]);
    r4[4 + 2 * k + 1] = make_float4(lm[k], cw[k], cw[k + 1], 0.0f);
  }
}

// Monotonic linear-rational spline (approx rcp/sqrt; tol 0.099 >> 1ulp).
__device__ __forceinline__ float spline_eval(float z, float xk, float xk1,
                                             float yk, float yk1,
                                             float dk, float dk1, float lam) {
  float xc = fminf(fmaxf(z, -5.0f), 5.0f);
  float wk = xk1 - xk;
  float hk = yk1 - yk;
  float wb = __builtin_amdgcn_sqrtf(dk * rcpf(dk1));
  float wc = fmaf(lam, dk, (1.0f - lam) * wb * dk1) * wk * rcpf(hk);
  float ya = yk;
  float yb = yk + hk;
  float yc = fmaf(lam * wb, yb, (1.0f - lam) * ya) * rcpf(fmaf(lam, wb, 1.0f - lam));
  float th = (xc - xk) * rcpf(wk);
  bool left = th <= lam;
  float num = left ? fmaf(ya, lam - th, wc * yc * th)
                   : fmaf(wc * yc, 1.0f - th, wb * yb * (th - lam));
  float den = left ? fmaf(wc, th, lam - th)
                   : fmaf(wc, 1.0f - th, wb * (th - lam));
  float y = num * rcpf(den);
  bool inside = (z >= -5.0f) && (z <= 5.0f);
  return inside ? y : z;
}

// ---------------- Layer-2 GEMM: H2T[m][o] = relu(sum_k W2[o][k]*h_k(u_m) + b2[o])
// Tile 64o x 32m, grid (64,4) = 256 blocks. Wave-split-K (64 k per wave).
// h_k(u) = relu(a_k u + b_k) is RECOMPUTED in-register per k (1 fma + 1 mul +
// 7 add + 8 max) from a 2KB (a,b) LDS array read at a wave-uniform address
// (broadcast, conflict-free) -- removes 2 of 3 ds_read_b128 per k, turning
// the LDS-bound loop (~9.2K cyc/CU) into a VALU-bound ~6.3K.
__global__ __launch_bounds__(256) void k_gemm2(const float* __restrict__ W1,
                                               const float* __restrict__ b1,
                                               const float* __restrict__ W2,
                                               const float* __restrict__ b2) {
  __shared__ float sW[256 * 67];    // W2^T [k][o], stride 67 (2-way = free)
  __shared__ float2 sAB[256];       // (a_k, b_k)
  __shared__ float red[3 * 64 * 36];
  const int t = threadIdx.x;
  const int m0 = blockIdx.x * 32;
  const int o0 = blockIdx.y * 64;
  // ---- stage W2^T: k = 64c + 16seg + 4q + j keeps banks 2-way (free) ----
  {
    const int ol = t >> 2, seg = t & 3;
    const float* src = W2 + (size_t)(o0 + ol) * 256 + 16 * seg;
#pragma unroll
    for (int c = 0; c < 4; c++) {
#pragma unroll
      for (int q = 0; q < 4; q++) {
        float4 v = *(const float4*)(src + 64 * c + 4 * q);
        const int k = 64 * c + 16 * seg + 4 * q;
        sW[(k + 0) * 67 + ol] = v.x;
        sW[(k + 1) * 67 + ol] = v.y;
        sW[(k + 2) * 67 + ol] = v.z;
        sW[(k + 3) * 67 + ol] = v.w;
      }
    }
  }
  sAB[t] = make_float2(W1[2 * t], b1[t]);
  __syncthreads();
  // ---- wave-split-K FMA phase: wave w owns k in [64w, 64w+64) ----
  const int w = t >> 6, lane = t & 63;
  const int tp = lane >> 2, tm = lane & 3;  // o = o0+4tp+i, m = m0+8tm+j
  const float u0 = fmaf((float)(m0 + 8 * tm), DELTA, U_LO);
  float acc[4][8] = {};
  const int kb = w * 64;
#pragma unroll 8
  for (int kk = 0; kk < 64; kk++) {
    const int k = kb + kk;
    float4 av = *(const float4*)&sW[k * 67 + 4 * tp];
    float2 ab = sAB[k];
    float t0 = fmaf(ab.x, u0, ab.y);
    float st = ab.x * DELTA;
    float h[8];
#pragma unroll
    for (int j = 0; j < 8; j++) h[j] = fmaxf(fmaf((float)j, st, t0), 0.0f);
#pragma unroll
    for (int i = 0; i < 4; i++) {
      const float aa = (i == 0) ? av.x : (i == 1) ? av.y : (i == 2) ? av.z : av.w;
#pragma unroll
      for (int j = 0; j < 8; j++) acc[i][j] = fmaf(aa, h[j], acc[i][j]);
    }
  }
  if (w > 0) {
#pragma unroll
    for (int i = 0; i < 4; i++) {
      *(float4*)&red[((w - 1) * 64 + lane) * 36 + 8 * i] =
          make_float4(acc[i][0], acc[i][1], acc[i][2], acc[i][3]);
      *(float4*)&red[((w - 1) * 64 + lane) * 36 + 8 * i + 4] =
          make_float4(acc[i][4], acc[i][5], acc[i][6], acc[i][7]);
    }
  }
  __syncthreads();
  if (w == 0) {
#pragma unroll
    for (int v = 0; v < 3; v++) {
#pragma unroll
      for (int i = 0; i < 4; i++) {
        float4 r0 = *(const float4*)&red[(v * 64 + lane) * 36 + 8 * i];
        float4 r1 = *(const float4*)&red[(v * 64 + lane) * 36 + 8 * i + 4];
        acc[i][0] += r0.x; acc[i][1] += r0.y; acc[i][2] += r0.z; acc[i][3] += r0.w;
        acc[i][4] += r1.x; acc[i][5] += r1.y; acc[i][6] += r1.z; acc[i][7] += r1.w;
      }
    }
    float4 bb = *(const float4*)&b2[o0 + 4 * tp];
#pragma unroll
    for (int j = 0; j < 8; j++) {
      float4 r;
      r.x = fmaxf(acc[0][j] + bb.x, 0.0f);
      r.y = fmaxf(acc[1][j] + bb.y, 0.0f);
      r.z = fmaxf(acc[2][j] + bb.z, 0.0f);
      r.w = fmaxf(acc[3][j] + bb.w, 0.0f);
      *(float4*)&g_H2T[(size_t)(m0 + 8 * tm + j) * 256 + o0 + 4 * tp] = r;
    }
  }
}

// ---------------- Layer-3 GEMM (odd rows of W3) + param processing -> g_table
// Tile 64p x 16m, grid 128 blocks, wave-split-K (16 acc/lane).
__global__ __launch_bounds__(256) void k_gemm3proc(const float* __restrict__ W3,
                                                   const float* __restrict__ b3) {
  __shared__ float sW[256 * 67];   // W3odd^T [k][p]
  __shared__ float sH[256 * 20];   // H2 slice [k][m']; aliased as red buffer
  __shared__ float raws[64 * 20];  // [p][m']
  const int t = threadIdx.x;
  const int m0 = blockIdx.x * MT3;
  // ---- stage W3odd^T (conflict-free k decomposition) ----
  {
    const int ol = t >> 2, seg = t & 3;
    const int row = (ol < 63) ? (2 * ol + 1) : 1;
    const float* src = W3 + (size_t)row * 256 + 16 * seg;
#pragma unroll
    for (int c = 0; c < 4; c++) {
#pragma unroll
      for (int q = 0; q < 4; q++) {
        float4 v = *(const float4*)(src + 64 * c + 4 * q);
        const int k = 64 * c + 16 * seg + 4 * q;
        sW[(k + 0) * 67 + ol] = v.x;
        sW[(k + 1) * 67 + ol] = v.y;
        sW[(k + 2) * 67 + ol] = v.z;
        sW[(k + 3) * 67 + ol] = v.w;
      }
    }
  }
  // ---- stage H2T slice (contiguous rows -> coalesced) into [k][m'] ----
  {
    const int j = t & 15, c = t >> 4;  // m-row j, k-chunk c
    const float* src = g_H2T + (size_t)(m0 + j) * 256 + 16 * c;
#pragma unroll
    for (int q = 0; q < 4; q++) {
      float4 v = *(const float4*)(src + 4 * q);
      const int k = 16 * c + 4 * q;
      sH[(k + 0) * 20 + j] = v.x;
      sH[(k + 1) * 20 + j] = v.y;
      sH[(k + 2) * 20 + j] = v.z;
      sH[(k + 3) * 20 + j] = v.w;
    }
  }
  __syncthreads();
  // ---- wave-split-K FMA phase ----
  const int w = t >> 6, lane = t & 63;
  const int tp = lane >> 2, tm = lane & 3;  // p = 4tp+i, m = 4tm+j
  float acc[4][4] = {};
  const int kb = w * 64;
#pragma unroll 8
  for (int kk = 0; kk < 64; kk++) {
    const int k = kb + kk;
    float4 av = *(const float4*)&sW[k * 67 + 4 * tp];
    float4 bv = *(const float4*)&sH[k * 20 + 4 * tm];
    acc[0][0] = fmaf(av.x, bv.x, acc[0][0]); acc[0][1] = fmaf(av.x, bv.y, acc[0][1]);
    acc[0][2] = fmaf(av.x, bv.z, acc[0][2]); acc[0][3] = fmaf(av.x, bv.w, acc[0][3]);
    acc[1][0] = fmaf(av.y, bv.x, acc[1][0]); acc[1][1] = fmaf(av.y, bv.y, acc[1][1]);
    acc[1][2] = fmaf(av.y, bv.z, acc[1][2]); acc[1][3] = fmaf(av.y, bv.w, acc[1][3]);
    acc[2][0] = fmaf(av.z, bv.x, acc[2][0]); acc[2][1] = fmaf(av.z, bv.y, acc[2][1]);
    acc[2][2] = fmaf(av.z, bv.z, acc[2][2]); acc[2][3] = fmaf(av.z, bv.w, acc[2][3]);
    acc[3][0] = fmaf(av.w, bv.x, acc[3][0]); acc[3][1] = fmaf(av.w, bv.y, acc[3][1]);
    acc[3][2] = fmaf(av.w, bv.z, acc[3][2]); acc[3][3] = fmaf(av.w, bv.w, acc[3][3]);
  }
  __syncthreads();  // sH dead; alias as red buffer
  if (w > 0) {
#pragma unroll
    for (int i = 0; i < 4; i++)
      *(float4*)&sH[((w - 1) * 64 + lane) * 20 + 4 * i] =
          make_float4(acc[i][0], acc[i][1], acc[i][2], acc[i][3]);
  }
  __syncthreads();
  if (w == 0) {
#pragma unroll
    for (int v = 0; v < 3; v++) {
#pragma unroll
      for (int i = 0; i < 4; i++) {
        float4 r = *(const float4*)&sH[(v * 64 + lane) * 20 + 4 * i];
        acc[i][0] += r.x; acc[i][1] += r.y; acc[i][2] += r.z; acc[i][3] += r.w;
      }
    }
#pragma unroll
    for (int i = 0; i < 4; i++) {
      const int p = 4 * tp + i;
      const int bi = (p < 63) ? (2 * p + 1) : 1;
      const float bias = b3[bi];
      *(float4*)&raws[p * 20 + 4 * tm] =
          make_float4(acc[i][0] + bias, acc[i][1] + bias,
                      acc[i][2] + bias, acc[i][3] + bias);
    }
  }
  __syncthreads();
  if (t < MT3) process_column(&raws[t], 20, g_table + (size_t)(m0 + t) * REC);
  if (t == 64 && blockIdx.x == 0) process_column(b3, 2, g_knots0);  // dim-0 constant knots
}

// ---------------- Main flow kernel: 4 steps per sample
__global__ __launch_bounds__(256) void k_main(const float* __restrict__ x,
                                              float* __restrict__ out) {
  __shared__ __attribute__((aligned(16))) float kn0[REC];
  for (int j = threadIdx.x; j < REC; j += 256) kn0[j] = g_knots0[j];
  __syncthreads();
  // dim-0 knots: unpack once into registers (reused all 4 steps)
  float kf0[16];
  {
    uint4 q0 = *(const uint4*)(kn0);
    uint4 q1 = *(const uint4*)(kn0 + 4);
    unpack8(q0, kf0);
    unpack8(q1, kf0 + 8);
  }
  const int i = blockIdx.x * 256 + threadIdx.x;
  const float2 xv = ((const float2*)x)[i];
  float z0 = xv.x, z1 = xv.y;
  ((float2*)out)[i] = xv;  // step 0 = input
  for (int t = 0; t < 4; t++) {
    // ---- dim 1: table lookup keyed by u = current z0 ----
    float tt = (z0 - U_LO) * INV_DELTA;
    int i0 = (int)floorf(tt);
    i0 = min(max(i0, 0), M_GRID - 2);
    float f = fminf(fmaxf(tt - (float)i0, 0.0f), 1.0f);
    const float* r0 = g_table + (size_t)i0 * REC;
    // bin search on r0's fp16 knots (1 cache line)
    float kf[16];
    {
      uint4 q0 = *(const uint4*)(r0);
      uint4 q1 = *(const uint4*)(r0 + 4);
      unpack8(q0, kf);
      unpack8(q1, kf + 8);
    }
    float xc1 = fminf(fmaxf(z1, -5.0f), 5.0f);
    int k1 = 0;
#pragma unroll
    for (int j = 1; j < 16; j++) k1 += (xc1 >= kf[j]) ? 1 : 0;
    // bin chunks (fp32, one line each from r0 and r1)
    const float* c0 = r0 + 16 + 8 * k1;
    float4 A0 = *(const float4*)c0;
    float4 A1 = *(const float4*)(c0 + 4);
    float4 B0 = *(const float4*)(c0 + REC);
    float4 B1 = *(const float4*)(c0 + REC + 4);
    float yk  = fmaf(f, B0.x - A0.x, A0.x);
    float yk1 = fmaf(f, B0.y - A0.y, A0.y);
    float dk  = fmaf(f, B0.z - A0.z, A0.z);
    float dk1 = fmaf(f, B0.w - A0.w, A0.w);
    float lam = fmaf(f, B1.x - A1.x, A1.x);
    float xk  = fmaf(f, B1.y - A1.y, A1.y);
    float xk1 = fmaf(f, B1.z - A1.z, A1.z);
    float z1n = spline_eval(z1, xk, xk1, yk, yk1, dk, dk1, lam);
    // ---- dim 0: constant knots (registers) + chunks from LDS ----
    float xc0 = fminf(fmaxf(z0, -5.0f), 5.0f);
    int k0 = 0;
#pragma unroll
    for (int j = 1; j < 16; j++) k0 += (xc0 >= kf0[j]) ? 1 : 0;
    const float* c = kn0 + 16 + 8 * k0;
    float4 C0 = *(const float4*)c;
    float4 C1 = *(const float4*)(c + 4);
    float z0n = spline_eval(z0, C1.y, C1.z, C0.x, C0.y, C0.z, C0.w, C1.x);
    z0 = z0n; z1 = z1n;
    ((float2*)(out + (size_t)(t + 1) * (N_SAMPLES * 2)))[i] = make_float2(z0, z1);
  }
}

extern "C" void kernel_launch(void* const* d_in, const int* in_sizes, int n_in,
                              void* d_out, int out_size, void* d_ws, size_t ws_size,
                              hipStream_t stream) {
  const float* x  = (const float*)d_in[0];
  const float* W1 = (const float*)d_in[1];
  const float* b1 = (const float*)d_in[2];
  const float* W2 = (const float*)d_in[3];
  const float* b2 = (const float*)d_in[4];
  const float* W3 = (const float*)d_in[5];
  const float* b3 = (const float*)d_in[6];
  float* out = (float*)d_out;
  hipLaunchKernelGGL(k_gemm2, dim3(M_GRID / 32, 4), dim3(256), 0, stream, W1, b1, W2, b2);
  hipLaunchKernelGGL(k_gemm3proc, dim3(M_GRID / MT3), dim3(256), 0, stream, W3, b3);
  hipLaunchKernelGGL(k_main, dim3(N_SAMPLES / 256), dim3(256), 0, stream, x, out);
}

// Round 4
// 103.084 us; speedup vs baseline: 1.1860x; 1.0097x over previous
//
#include <hip/hip_runtime.h>
#include <hip/hip_fp16.h>
#include <math.h>

#define N_SAMPLES 131072
#define HIDDEN    256
#define M_GRID    2048
#define REC       72           // floats per table record (288B; 16B-aligned)
#define U_LO      (-8.0f)
#define DELTA     0.0078125f   // 16 / 2048
#define INV_DELTA 128.0f
#define MT3       16           // m-tile of the layer-3 kernel
#define STR2      69           // dword stride of packed fp16 weight tiles

// Record layout (72 floats / 288 B):
//   float ofs 0..7  : 16 fp16 knots cw[0..15]  (search-only; cw[16]=5 implicit)
//   float ofs 8+4k  : uint4 chunk k = {h2(ch[k],ch[k+1]), h2(dv[k],dv[k+1]),
//                                      h2(lam[k],cw[k]),  h2(cw[k+1],0)}
// All params fp16 (ulp@5 ~ 2e-3; spline continuity bounds bin-edge effects).
__device__ __attribute__((aligned(16))) float g_H2T[M_GRID * HIDDEN];  // [m][k], 2 MB
__device__ __attribute__((aligned(16))) float g_table[M_GRID * REC];   // 576 KB
__device__ __attribute__((aligned(16))) float g_knots0[REC];

__device__ __forceinline__ float rcpf(float x) { return __builtin_amdgcn_rcpf(x); }

__device__ __forceinline__ float softplusf(float x) {
  return fmaxf(x, 0.0f) + log1pf(expf(-fabsf(x)));
}

__device__ __forceinline__ unsigned int packh2(float a, float b) {
  __half2 h = __floats2half2_rn(a, b);
  return *(unsigned int*)&h;
}

__device__ __forceinline__ void unpack8(uint4 u, float* f) {
  float2 t;
  t = __half22float2(*(__half2*)&u.x); f[0] = t.x; f[1] = t.y;
  t = __half22float2(*(__half2*)&u.y); f[2] = t.x; f[3] = t.y;
  t = __half22float2(*(__half2*)&u.z); f[4] = t.x; f[5] = t.y;
  t = __half22float2(*(__half2*)&u.w); f[6] = t.x; f[7] = t.y;
}

// Process one 63-value raw-param column into a 288B record.
__device__ void process_column(const float* __restrict__ raw, int stride,
                               float* __restrict__ rec) {
  float v[16];
  float cw[17], ch[17], dv[17], lm[16];
  // ---- widths -> cw ----
  float mx = -1e30f;
#pragma unroll
  for (int k = 0; k < 16; k++) { v[k] = raw[k * stride]; mx = fmaxf(mx, v[k]); }
  float s = 0.0f;
#pragma unroll
  for (int k = 0; k < 16; k++) { v[k] = expf(v[k] - mx); s += v[k]; }
  float scl = 0.984f / s;  // (1 - MIN_BIN*K)
  cw[0] = -5.0f;
  float a = 0.0f;
#pragma unroll
  for (int k = 0; k < 16; k++) {
    a += fmaf(v[k], scl, 0.001f);
    cw[k + 1] = fmaf(a, 10.0f, -5.0f);
  }
  cw[16] = 5.0f;
  // ---- heights -> ch ----
  mx = -1e30f;
#pragma unroll
  for (int k = 0; k < 16; k++) { v[k] = raw[(16 + k) * stride]; mx = fmaxf(mx, v[k]); }
  s = 0.0f;
#pragma unroll
  for (int k = 0; k < 16; k++) { v[k] = expf(v[k] - mx); s += v[k]; }
  scl = 0.984f / s;
  ch[0] = -5.0f;
  a = 0.0f;
#pragma unroll
  for (int k = 0; k < 16; k++) {
    a += fmaf(v[k], scl, 0.001f);
    ch[k + 1] = fmaf(a, 10.0f, -5.0f);
  }
  ch[16] = 5.0f;
  // ---- derivatives (boundary = 1) ----
  dv[0] = 1.0f; dv[16] = 1.0f;
#pragma unroll
  for (int j = 0; j < 15; j++) dv[j + 1] = 0.001f + softplusf(raw[(32 + j) * stride]);
  // ---- lambdas ----
#pragma unroll
  for (int k = 0; k < 16; k++) {
    float xx = raw[(47 + k) * stride];
    lm[k] = fmaf(0.95f, 1.0f / (1.0f + expf(-xx)), 0.025f);
  }
  // ---- emit: fp16 knot row + fp16 chunks ----
  uint4* u4 = (uint4*)rec;
  u4[0] = make_uint4(packh2(cw[0], cw[1]),  packh2(cw[2], cw[3]),
                     packh2(cw[4], cw[5]),  packh2(cw[6], cw[7]));
  u4[1] = make_uint4(packh2(cw[8], cw[9]),  packh2(cw[10], cw[11]),
                     packh2(cw[12], cw[13]), packh2(cw[14], cw[15]));
#pragma unroll
  for (int k = 0; k < 16; k++) {
    u4[2 + k] = make_uint4(packh2(ch[k], ch[k + 1]), packh2(dv[k], dv[k + 1]),
                           packh2(lm[k], cw[k]),     packh2(cw[k + 1], 0.0f));
  }
}

// Monotonic linear-rational spline (approx rcp/sqrt; tol 0.099 >> 1ulp).
__device__ __forceinline__ float spline_eval(float z, float xk, float xk1,
                                             float yk, float yk1,
                                             float dk, float dk1, float lam) {
  float xc = fminf(fmaxf(z, -5.0f), 5.0f);
  float wk = xk1 - xk;
  float hk = yk1 - yk;
  float wb = __builtin_amdgcn_sqrtf(dk * rcpf(dk1));
  float wc = fmaf(lam, dk, (1.0f - lam) * wb * dk1) * wk * rcpf(hk);
  float ya = yk;
  float yb = yk + hk;
  float yc = fmaf(lam * wb, yb, (1.0f - lam) * ya) * rcpf(fmaf(lam, wb, 1.0f - lam));
  float th = (xc - xk) * rcpf(wk);
  bool left = th <= lam;
  float num = left ? fmaf(ya, lam - th, wc * yc * th)
                   : fmaf(wc * yc, 1.0f - th, wb * yb * (th - lam));
  float den = left ? fmaf(wc, th, lam - th)
                   : fmaf(wc, 1.0f - th, wb * (th - lam));
  float y = num * rcpf(den);
  bool inside = (z >= -5.0f) && (z <= 5.0f);
  return inside ? y : z;
}

// ---------------- Layer-2 GEMM: H2T[m][o] = relu(sum_k W2[o][k]*h_k(u_m) + b2[o])
// Tile 64o x 32m, grid (64,4) = 256 blocks, wave-split-K.
// sW packed fp16: dword(k2*STR2+o) = half2(W2[o][2k2], W2[o][2k2+1]) -> one
// ds_read_b128 feeds TWO k-iterations (LDS-read instrs halved); stage writes
// halved (32 b32/thread); LDS 98KB -> 65KB. h_k(u) recomputed in-register.
__global__ __launch_bounds__(256) void k_gemm2(const float* __restrict__ W1,
                                               const float* __restrict__ b1,
                                               const float* __restrict__ W2,
                                               const float* __restrict__ b2) {
  __shared__ unsigned int sW[128 * STR2];  // 35.3 KB
  __shared__ float2 sAB[256];              // 2 KB
  __shared__ float red[3 * 64 * 36];       // 27.6 KB
  const int t = threadIdx.x;
  const int m0 = blockIdx.x * 32;
  const int o0 = blockIdx.y * 64;
  // ---- stage packed W2^T: k = 64c+16seg+4q+j; 2-way bank (free) ----
  {
    const int ol = t >> 2, seg = t & 3;
    const float* src = W2 + (size_t)(o0 + ol) * 256 + 16 * seg;
#pragma unroll
    for (int c = 0; c < 4; c++) {
#pragma unroll
      for (int q = 0; q < 4; q++) {
        float4 v = *(const float4*)(src + 64 * c + 4 * q);
        const int k2 = (64 * c + 16 * seg + 4 * q) >> 1;
        sW[(k2 + 0) * STR2 + ol] = packh2(v.x, v.y);
        sW[(k2 + 1) * STR2 + ol] = packh2(v.z, v.w);
      }
    }
  }
  sAB[t] = make_float2(W1[2 * t], b1[t]);
  __syncthreads();
  // ---- wave-split-K: wave w owns k-pairs [32w, 32w+32) ----
  const int w = t >> 6, lane = t & 63;
  const int tp = lane >> 2, tm = lane & 3;  // o = o0+4tp+i, m = m0+8tm+j
  const float u0 = fmaf((float)(m0 + 8 * tm), DELTA, U_LO);
  float acc[4][8] = {};
  const int kb2 = w * 32;
#pragma unroll 4
  for (int kk = 0; kk < 32; kk++) {
    const int k2 = kb2 + kk;
    uint4 ap = *(const uint4*)&sW[k2 * STR2 + 4 * tp];
    float2 a0 = __half22float2(*(__half2*)&ap.x);
    float2 a1 = __half22float2(*(__half2*)&ap.y);
    float2 a2 = __half22float2(*(__half2*)&ap.z);
    float2 a3 = __half22float2(*(__half2*)&ap.w);
    float2 abe = sAB[2 * k2];
    float2 abo = sAB[2 * k2 + 1];
    float t0e = fmaf(abe.x, u0, abe.y), ste = abe.x * DELTA;
    float t0o = fmaf(abo.x, u0, abo.y), sto = abo.x * DELTA;
    float he[8], ho[8];
#pragma unroll
    for (int j = 0; j < 8; j++) {
      he[j] = fmaxf(fmaf((float)j, ste, t0e), 0.0f);
      ho[j] = fmaxf(fmaf((float)j, sto, t0o), 0.0f);
    }
#pragma unroll
    for (int j = 0; j < 8; j++) {
      acc[0][j] = fmaf(a0.x, he[j], acc[0][j]);
      acc[1][j] = fmaf(a1.x, he[j], acc[1][j]);
      acc[2][j] = fmaf(a2.x, he[j], acc[2][j]);
      acc[3][j] = fmaf(a3.x, he[j], acc[3][j]);
      acc[0][j] = fmaf(a0.y, ho[j], acc[0][j]);
      acc[1][j] = fmaf(a1.y, ho[j], acc[1][j]);
      acc[2][j] = fmaf(a2.y, ho[j], acc[2][j]);
      acc[3][j] = fmaf(a3.y, ho[j], acc[3][j]);
    }
  }
  if (w > 0) {
#pragma unroll
    for (int i = 0; i < 4; i++) {
      *(float4*)&red[((w - 1) * 64 + lane) * 36 + 8 * i] =
          make_float4(acc[i][0], acc[i][1], acc[i][2], acc[i][3]);
      *(float4*)&red[((w - 1) * 64 + lane) * 36 + 8 * i + 4] =
          make_float4(acc[i][4], acc[i][5], acc[i][6], acc[i][7]);
    }
  }
  __syncthreads();
  if (w == 0) {
#pragma unroll
    for (int v = 0; v < 3; v++) {
#pragma unroll
      for (int i = 0; i < 4; i++) {
        float4 r0 = *(const float4*)&red[(v * 64 + lane) * 36 + 8 * i];
        float4 r1 = *(const float4*)&red[(v * 64 + lane) * 36 + 8 * i + 4];
        acc[i][0] += r0.x; acc[i][1] += r0.y; acc[i][2] += r0.z; acc[i][3] += r0.w;
        acc[i][4] += r1.x; acc[i][5] += r1.y; acc[i][6] += r1.z; acc[i][7] += r1.w;
      }
    }
    float4 bb = *(const float4*)&b2[o0 + 4 * tp];
#pragma unroll
    for (int j = 0; j < 8; j++) {
      float4 r;
      r.x = fmaxf(acc[0][j] + bb.x, 0.0f);
      r.y = fmaxf(acc[1][j] + bb.y, 0.0f);
      r.z = fmaxf(acc[2][j] + bb.z, 0.0f);
      r.w = fmaxf(acc[3][j] + bb.w, 0.0f);
      *(float4*)&g_H2T[(size_t)(m0 + 8 * tm + j) * 256 + o0 + 4 * tp] = r;
    }
  }
}

// ---------------- Layer-3 GEMM (odd rows of W3) + param processing -> g_table
// Tile 64p x 16m, grid 128 blocks, wave-split-K; sW AND sH fp16 pair-packed
// (2 ds_read_b128 per TWO k-iterations). LDS 94KB -> 64.5KB.
__global__ __launch_bounds__(256) void k_gemm3proc(const float* __restrict__ W3,
                                                   const float* __restrict__ b3) {
  __shared__ unsigned int sW[128 * STR2];  // 35.3 KB
  __shared__ unsigned int sH[128 * 17];    // 8.7 KB
  __shared__ float red[3 * 64 * 20];       // 15.4 KB
  __shared__ float raws[64 * 20];          // 5.1 KB
  const int t = threadIdx.x;
  const int m0 = blockIdx.x * MT3;
  // ---- stage packed W3odd^T ----
  {
    const int ol = t >> 2, seg = t & 3;
    const int row = (ol < 63) ? (2 * ol + 1) : 1;
    const float* src = W3 + (size_t)row * 256 + 16 * seg;
#pragma unroll
    for (int c = 0; c < 4; c++) {
#pragma unroll
      for (int q = 0; q < 4; q++) {
        float4 v = *(const float4*)(src + 64 * c + 4 * q);
        const int k2 = (64 * c + 16 * seg + 4 * q) >> 1;
        sW[(k2 + 0) * STR2 + ol] = packh2(v.x, v.y);
        sW[(k2 + 1) * STR2 + ol] = packh2(v.z, v.w);
      }
    }
  }
  // ---- stage packed H2T slice [k2][m'] ----
  {
    const int j = t & 15, c = t >> 4;  // m-row j, k-chunk c
    const float* src = g_H2T + (size_t)(m0 + j) * 256 + 16 * c;
#pragma unroll
    for (int q = 0; q < 4; q++) {
      float4 v = *(const float4*)(src + 4 * q);
      const int k2 = (16 * c + 4 * q) >> 1;
      sH[(k2 + 0) * 17 + j] = packh2(v.x, v.y);
      sH[(k2 + 1) * 17 + j] = packh2(v.z, v.w);
    }
  }
  __syncthreads();
  // ---- wave-split-K FMA phase ----
  const int w = t >> 6, lane = t & 63;
  const int tp = lane >> 2, tm = lane & 3;  // p = 4tp+i, m = 4tm+j
  float acc[4][4] = {};
  const int kb2 = w * 32;
#pragma unroll 4
  for (int kk = 0; kk < 32; kk++) {
    const int k2 = kb2 + kk;
    uint4 ap = *(const uint4*)&sW[k2 * STR2 + 4 * tp];
    uint4 bp = *(const uint4*)&sH[k2 * 17 + 4 * tm];
    float2 a0 = __half22float2(*(__half2*)&ap.x);
    float2 a1 = __half22float2(*(__half2*)&ap.y);
    float2 a2 = __half22float2(*(__half2*)&ap.z);
    float2 a3 = __half22float2(*(__half2*)&ap.w);
    float2 b0 = __half22float2(*(__half2*)&bp.x);
    float2 b1v = __half22float2(*(__half2*)&bp.y);
    float2 b2v = __half22float2(*(__half2*)&bp.z);
    float2 b3v = __half22float2(*(__half2*)&bp.w);
    float ae[4] = {a0.x, a1.x, a2.x, a3.x};
    float ao[4] = {a0.y, a1.y, a2.y, a3.y};
    float be[4] = {b0.x, b1v.x, b2v.x, b3v.x};
    float bo[4] = {b0.y, b1v.y, b2v.y, b3v.y};
#pragma unroll
    for (int i = 0; i < 4; i++) {
#pragma unroll
      for (int j = 0; j < 4; j++) {
        acc[i][j] = fmaf(ae[i], be[j], acc[i][j]);
        acc[i][j] = fmaf(ao[i], bo[j], acc[i][j]);
      }
    }
  }
  if (w > 0) {
#pragma unroll
    for (int i = 0; i < 4; i++)
      *(float4*)&red[((w - 1) * 64 + lane) * 20 + 4 * i] =
          make_float4(acc[i][0], acc[i][1], acc[i][2], acc[i][3]);
  }
  __syncthreads();
  if (w == 0) {
#pragma unroll
    for (int v = 0; v < 3; v++) {
#pragma unroll
      for (int i = 0; i < 4; i++) {
        float4 r = *(const float4*)&red[(v * 64 + lane) * 20 + 4 * i];
        acc[i][0] += r.x; acc[i][1] += r.y; acc[i][2] += r.z; acc[i][3] += r.w;
      }
    }
#pragma unroll
    for (int i = 0; i < 4; i++) {
      const int p = 4 * tp + i;
      const int bi = (p < 63) ? (2 * p + 1) : 1;
      const float bias = b3[bi];
      *(float4*)&raws[p * 20 + 4 * tm] =
          make_float4(acc[i][0] + bias, acc[i][1] + bias,
                      acc[i][2] + bias, acc[i][3] + bias);
    }
  }
  __syncthreads();
  if (t < MT3) process_column(&raws[t], 20, g_table + (size_t)(m0 + t) * REC);
  if (t == 64 && blockIdx.x == 0) process_column(b3, 2, g_knots0);  // dim-0 constant knots
}

// ---------------- Main flow kernel: 4 steps per sample
__global__ __launch_bounds__(256) void k_main(const float* __restrict__ x,
                                              float* __restrict__ out) {
  __shared__ __attribute__((aligned(16))) float kn0[REC];
  for (int j = threadIdx.x; j < REC; j += 256) kn0[j] = g_knots0[j];
  __syncthreads();
  // dim-0 knots: unpack once into registers (reused all 4 steps)
  float kf0[16];
  {
    uint4 q0 = *(const uint4*)(kn0);
    uint4 q1 = *(const uint4*)(kn0 + 4);
    unpack8(q0, kf0);
    unpack8(q1, kf0 + 8);
  }
  const int i = blockIdx.x * 256 + threadIdx.x;
  const float2 xv = ((const float2*)x)[i];
  float z0 = xv.x, z1 = xv.y;
  ((float2*)out)[i] = xv;  // step 0 = input
  for (int t = 0; t < 4; t++) {
    // ---- dim 1: table lookup keyed by u = current z0 ----
    float tt = (z0 - U_LO) * INV_DELTA;
    int i0 = (int)floorf(tt);
    i0 = min(max(i0, 0), M_GRID - 2);
    float f = fminf(fmaxf(tt - (float)i0, 0.0f), 1.0f);
    const float* r0 = g_table + (size_t)i0 * REC;
    // bin search on r0's fp16 knots (2 loads, same cache line)
    float kf[16];
    {
      uint4 q0 = *(const uint4*)(r0);
      uint4 q1 = *(const uint4*)(r0 + 4);
      unpack8(q0, kf);
      unpack8(q1, kf + 8);
    }
    float xc1 = fminf(fmaxf(z1, -5.0f), 5.0f);
    int k1 = 0;
#pragma unroll
    for (int j = 1; j < 16; j++) k1 += (xc1 >= kf[j]) ? 1 : 0;
    // fp16 chunks: ONE dwordx4 from r0 and one from r1
    const float* c0 = r0 + 8 + 4 * k1;
    uint4 A = *(const uint4*)c0;
    uint4 B = *(const uint4*)(c0 + REC);
    float2 Ay = __half22float2(*(__half2*)&A.x);  // yk, yk1
    float2 Ad = __half22float2(*(__half2*)&A.y);  // dk, dk1
    float2 Al = __half22float2(*(__half2*)&A.z);  // lam, xk
    float2 Ax = __half22float2(*(__half2*)&A.w);  // xk1, -
    float2 By = __half22float2(*(__half2*)&B.x);
    float2 Bd = __half22float2(*(__half2*)&B.y);
    float2 Bl = __half22float2(*(__half2*)&B.z);
    float2 Bx = __half22float2(*(__half2*)&B.w);
    float yk  = fmaf(f, By.x - Ay.x, Ay.x);
    float yk1 = fmaf(f, By.y - Ay.y, Ay.y);
    float dk  = fmaf(f, Bd.x - Ad.x, Ad.x);
    float dk1 = fmaf(f, Bd.y - Ad.y, Ad.y);
    float lam = fmaf(f, Bl.x - Al.x, Al.x);
    float xk  = fmaf(f, Bl.y - Al.y, Al.y);
    float xk1 = fmaf(f, Bx.x - Ax.x, Ax.x);
    float z1n = spline_eval(z1, xk, xk1, yk, yk1, dk, dk1, lam);
    // ---- dim 0: constant knots (registers) + fp16 chunk from LDS ----
    float xc0 = fminf(fmaxf(z0, -5.0f), 5.0f);
    int k0 = 0;
#pragma unroll
    for (int j = 1; j < 16; j++) k0 += (xc0 >= kf0[j]) ? 1 : 0;
    uint4 C = *(const uint4*)&kn0[8 + 4 * k0];
    float2 Cy = __half22float2(*(__half2*)&C.x);
    float2 Cd = __half22float2(*(__half2*)&C.y);
    float2 Cl = __half22float2(*(__half2*)&C.z);
    float2 Cx = __half22float2(*(__half2*)&C.w);
    float z0n = spline_eval(z0, Cl.y, Cx.x, Cy.x, Cy.y, Cd.x, Cd.y, Cl.x);
    z0 = z0n; z1 = z1n;
    ((float2*)(out + (size_t)(t + 1) * (N_SAMPLES * 2)))[i] = make_float2(z0, z1);
  }
}

extern "C" void kernel_launch(void* const* d_in, const int* in_sizes, int n_in,
                              void* d_out, int out_size, void* d_ws, size_t ws_size,
                              hipStream_t stream) {
  const float* x  = (const float*)d_in[0];
  const float* W1 = (const float*)d_in[1];
  const float* b1 = (const float*)d_in[2];
  const float* W2 = (const float*)d_in[3];
  const float* b2 = (const float*)d_in[4];
  const float* W3 = (const float*)d_in[5];
  const float* b3 = (const float*)d_in[6];
  float* out = (float*)d_out;
  hipLaunchKernelGGL(k_gemm2, dim3(M_GRID / 32, 4), dim3(256), 0, stream, W1, b1, W2, b2);
  hipLaunchKernelGGL(k_gemm3proc, dim3(M_GRID / MT3), dim3(256), 0, stream, W3, b3);
  hipLaunchKernelGGL(k_main, dim3(N_SAMPLES / 256), dim3(256), 0, stream, x, out);
}

// Round 5
// 89.996 us; speedup vs baseline: 1.3584x; 1.1454x over previous
//
#include <hip/hip_runtime.h>
#include <hip/hip_fp16.h>
#include <math.h>

#define N_SAMPLES 131072
#define HIDDEN    256
#define M_GRID    2048
#define REC       72           // floats per table record (288B; 16B-aligned)
#define U_LO      (-8.0f)
#define DELTA     0.0078125f   // 16 / 2048
#define INV_DELTA 128.0f
#define MT3       8            // m-tile of the layer-3 kernel (256 blocks)
#define STR2      69           // dword stride of packed fp16 weight tiles

// Record layout (72 floats / 288 B):
//   float ofs 0..7  : 16 fp16 knots cw[0..15]  (search-only; cw[16]=5 implicit)
//   float ofs 8+4k  : uint4 chunk k = {h2(ch[k],ch[k+1]), h2(dv[k],dv[k+1]),
//                                      h2(lam[k],cw[k]),  h2(cw[k+1],0)}
__device__ __attribute__((aligned(16))) float g_H2T[M_GRID * HIDDEN];  // [m][k], 2 MB
__device__ __attribute__((aligned(16))) float g_table[M_GRID * REC];   // 576 KB
__device__ __attribute__((aligned(16))) float g_knots0[REC];

__device__ __forceinline__ float rcpf(float x) { return __builtin_amdgcn_rcpf(x); }

__device__ __forceinline__ float softplusf(float x) {
  return fmaxf(x, 0.0f) + log1pf(expf(-fabsf(x)));
}

__device__ __forceinline__ unsigned int packh2(float a, float b) {
  __half2 h = __floats2half2_rn(a, b);
  return *(unsigned int*)&h;
}

__device__ __forceinline__ void unpack8(uint4 u, float* f) {
  float2 t;
  t = __half22float2(*(__half2*)&u.x); f[0] = t.x; f[1] = t.y;
  t = __half22float2(*(__half2*)&u.y); f[2] = t.x; f[3] = t.y;
  t = __half22float2(*(__half2*)&u.z); f[4] = t.x; f[5] = t.y;
  t = __half22float2(*(__half2*)&u.w); f[6] = t.x; f[7] = t.y;
}

// 16-lane-parallel spline-param processing. Lane kl of a 16-lane group handles
// bin kl of one column. wv/hv/dvr/lamv are the raw params for index kl.
// Replaces the serial 1-thread process_column (80 transcendentals -> 5).
__device__ __forceinline__ void process16(float wv, float hv, float dvr,
                                          float lamv, int kl,
                                          float* __restrict__ rec) {
  // ---- widths: softmax + prefix -> cw[kl], cw[kl+1] ----
  float mx = wv;
#pragma unroll
  for (int d = 1; d < 16; d <<= 1) mx = fmaxf(mx, __shfl_xor(mx, d, 16));
  float v = expf(wv - mx);
  float s = v;
#pragma unroll
  for (int d = 1; d < 16; d <<= 1) s += __shfl_xor(s, d, 16);
  float inc = fmaf(v, 0.984f * rcpf(s), 0.001f);
  float cum = inc;
#pragma unroll
  for (int d = 1; d < 16; d <<= 1) {
    float n = __shfl_up(cum, d, 16);
    if (kl >= d) cum += n;
  }
  float cwk1 = (kl == 15) ? 5.0f : fmaf(cum, 10.0f, -5.0f);
  float cwk = __shfl_up(cwk1, 1, 16);
  if (kl == 0) cwk = -5.0f;
  // ---- heights ----
  float mh = hv;
#pragma unroll
  for (int d = 1; d < 16; d <<= 1) mh = fmaxf(mh, __shfl_xor(mh, d, 16));
  float vh = expf(hv - mh);
  float sh = vh;
#pragma unroll
  for (int d = 1; d < 16; d <<= 1) sh += __shfl_xor(sh, d, 16);
  float inch = fmaf(vh, 0.984f * rcpf(sh), 0.001f);
  float cumh = inch;
#pragma unroll
  for (int d = 1; d < 16; d <<= 1) {
    float n = __shfl_up(cumh, d, 16);
    if (kl >= d) cumh += n;
  }
  float chk1 = (kl == 15) ? 5.0f : fmaf(cumh, 10.0f, -5.0f);
  float chk = __shfl_up(chk1, 1, 16);
  if (kl == 0) chk = -5.0f;
  // ---- derivatives (boundary = 1) ----
  float dvk1 = (kl < 15) ? (0.001f + softplusf(dvr)) : 1.0f;
  float dvk = __shfl_up(dvk1, 1, 16);
  if (kl == 0) dvk = 1.0f;
  // ---- lambda ----
  float lm = fmaf(0.95f, 1.0f / (1.0f + expf(-lamv)), 0.025f);
  // ---- emit chunk kl (16B per lane, 256B contiguous per column) ----
  uint4 ck = make_uint4(packh2(chk, chk1), packh2(dvk, dvk1),
                        packh2(lm, cwk), packh2(cwk1, 0.0f));
  ((uint4*)rec)[2 + kl] = ck;
  // ---- knot row: dword q = h2(cw[2q], cw[2q+1]), lanes 0..7 ----
  float cA = __shfl(cwk, 2 * kl, 16);
  float cB = __shfl(cwk, 2 * kl + 1, 16);
  if (kl < 8) ((unsigned int*)rec)[kl] = packh2(cA, cB);
}

// Monotonic linear-rational spline (approx rcp/sqrt; tol 0.099 >> 1ulp).
__device__ __forceinline__ float spline_eval(float z, float xk, float xk1,
                                             float yk, float yk1,
                                             float dk, float dk1, float lam) {
  float xc = fminf(fmaxf(z, -5.0f), 5.0f);
  float wk = xk1 - xk;
  float hk = yk1 - yk;
  float wb = __builtin_amdgcn_sqrtf(dk * rcpf(dk1));
  float wc = fmaf(lam, dk, (1.0f - lam) * wb * dk1) * wk * rcpf(hk);
  float ya = yk;
  float yb = yk + hk;
  float yc = fmaf(lam * wb, yb, (1.0f - lam) * ya) * rcpf(fmaf(lam, wb, 1.0f - lam));
  float th = (xc - xk) * rcpf(wk);
  bool left = th <= lam;
  float num = left ? fmaf(ya, lam - th, wc * yc * th)
                   : fmaf(wc * yc, 1.0f - th, wb * yb * (th - lam));
  float den = left ? fmaf(wc, th, lam - th)
                   : fmaf(wc, 1.0f - th, wb * (th - lam));
  float y = num * rcpf(den);
  bool inside = (z >= -5.0f) && (z <= 5.0f);
  return inside ? y : z;
}

// ---------------- Layer-2 GEMM: H2T[m][o] = relu(sum_k W2[o][k]*h_k(u_m) + b2[o])
// (unchanged from round 4; measured fine)
__global__ __launch_bounds__(256) void k_gemm2(const float* __restrict__ W1,
                                               const float* __restrict__ b1,
                                               const float* __restrict__ W2,
                                               const float* __restrict__ b2) {
  __shared__ unsigned int sW[128 * STR2];  // 35.3 KB
  __shared__ float2 sAB[256];              // 2 KB
  __shared__ float red[3 * 64 * 36];       // 27.6 KB
  const int t = threadIdx.x;
  const int m0 = blockIdx.x * 32;
  const int o0 = blockIdx.y * 64;
  {
    const int ol = t >> 2, seg = t & 3;
    const float* src = W2 + (size_t)(o0 + ol) * 256 + 16 * seg;
#pragma unroll
    for (int c = 0; c < 4; c++) {
#pragma unroll
      for (int q = 0; q < 4; q++) {
        float4 v = *(const float4*)(src + 64 * c + 4 * q);
        const int k2 = (64 * c + 16 * seg + 4 * q) >> 1;
        sW[(k2 + 0) * STR2 + ol] = packh2(v.x, v.y);
        sW[(k2 + 1) * STR2 + ol] = packh2(v.z, v.w);
      }
    }
  }
  sAB[t] = make_float2(W1[2 * t], b1[t]);
  __syncthreads();
  const int w = t >> 6, lane = t & 63;
  const int tp = lane >> 2, tm = lane & 3;
  const float u0 = fmaf((float)(m0 + 8 * tm), DELTA, U_LO);
  float acc[4][8] = {};
  const int kb2 = w * 32;
#pragma unroll 4
  for (int kk = 0; kk < 32; kk++) {
    const int k2 = kb2 + kk;
    uint4 ap = *(const uint4*)&sW[k2 * STR2 + 4 * tp];
    float2 a0 = __half22float2(*(__half2*)&ap.x);
    float2 a1 = __half22float2(*(__half2*)&ap.y);
    float2 a2 = __half22float2(*(__half2*)&ap.z);
    float2 a3 = __half22float2(*(__half2*)&ap.w);
    float2 abe = sAB[2 * k2];
    float2 abo = sAB[2 * k2 + 1];
    float t0e = fmaf(abe.x, u0, abe.y), ste = abe.x * DELTA;
    float t0o = fmaf(abo.x, u0, abo.y), sto = abo.x * DELTA;
    float he[8], ho[8];
#pragma unroll
    for (int j = 0; j < 8; j++) {
      he[j] = fmaxf(fmaf((float)j, ste, t0e), 0.0f);
      ho[j] = fmaxf(fmaf((float)j, sto, t0o), 0.0f);
    }
#pragma unroll
    for (int j = 0; j < 8; j++) {
      acc[0][j] = fmaf(a0.x, he[j], acc[0][j]);
      acc[1][j] = fmaf(a1.x, he[j], acc[1][j]);
      acc[2][j] = fmaf(a2.x, he[j], acc[2][j]);
      acc[3][j] = fmaf(a3.x, he[j], acc[3][j]);
      acc[0][j] = fmaf(a0.y, ho[j], acc[0][j]);
      acc[1][j] = fmaf(a1.y, ho[j], acc[1][j]);
      acc[2][j] = fmaf(a2.y, ho[j], acc[2][j]);
      acc[3][j] = fmaf(a3.y, ho[j], acc[3][j]);
    }
  }
  if (w > 0) {
#pragma unroll
    for (int i = 0; i < 4; i++) {
      *(float4*)&red[((w - 1) * 64 + lane) * 36 + 8 * i] =
          make_float4(acc[i][0], acc[i][1], acc[i][2], acc[i][3]);
      *(float4*)&red[((w - 1) * 64 + lane) * 36 + 8 * i + 4] =
          make_float4(acc[i][4], acc[i][5], acc[i][6], acc[i][7]);
    }
  }
  __syncthreads();
  if (w == 0) {
#pragma unroll
    for (int v = 0; v < 3; v++) {
#pragma unroll
      for (int i = 0; i < 4; i++) {
        float4 r0 = *(const float4*)&red[(v * 64 + lane) * 36 + 8 * i];
        float4 r1 = *(const float4*)&red[(v * 64 + lane) * 36 + 8 * i + 4];
        acc[i][0] += r0.x; acc[i][1] += r0.y; acc[i][2] += r0.z; acc[i][3] += r0.w;
        acc[i][4] += r1.x; acc[i][5] += r1.y; acc[i][6] += r1.z; acc[i][7] += r1.w;
      }
    }
    float4 bb = *(const float4*)&b2[o0 + 4 * tp];
#pragma unroll
    for (int j = 0; j < 8; j++) {
      float4 r;
      r.x = fmaxf(acc[0][j] + bb.x, 0.0f);
      r.y = fmaxf(acc[1][j] + bb.y, 0.0f);
      r.z = fmaxf(acc[2][j] + bb.z, 0.0f);
      r.w = fmaxf(acc[3][j] + bb.w, 0.0f);
      *(float4*)&g_H2T[(size_t)(m0 + 8 * tm + j) * 256 + o0 + 4 * tp] = r;
    }
  }
}

// ---------------- Layer-3 GEMM (odd rows of W3) + PARALLEL param processing
// Restructured vs round 4 (which measured 41-47us @ 2% occupancy, 96% stall):
//   - MT3 8, grid 256 blocks -> full CU coverage, LDS 48 KB
//   - process tail: 16 lanes per column via width-16 shuffles (128 threads
//     active vs 16; 5 transcendentals/thread vs 80)
//   - knots0 built CONCURRENTLY by wave 2's group 0 on block 0
__global__ __launch_bounds__(256) void k_gemm3proc(const float* __restrict__ W3,
                                                   const float* __restrict__ b3) {
  __shared__ unsigned int sW[128 * STR2];  // 35.3 KB packed W3odd^T [k2][p]
  __shared__ unsigned int sH[128 * 9];     // 4.6 KB packed H2 slice [k2][m]
  __shared__ float red[3 * 64 * 8];        // 6 KB wave partials
  __shared__ float raws[64 * 9];           // 2.3 KB [p][m]
  const int t = threadIdx.x;
  const int m0 = blockIdx.x * MT3;
  // ---- stage packed W3odd^T (k = 64c+16seg+4q+j decomposition) ----
  {
    const int ol = t >> 2, seg = t & 3;
    const int row = (ol < 63) ? (2 * ol + 1) : 1;
    const float* src = W3 + (size_t)row * 256 + 16 * seg;
#pragma unroll
    for (int c = 0; c < 4; c++) {
#pragma unroll
      for (int q = 0; q < 4; q++) {
        float4 v = *(const float4*)(src + 64 * c + 4 * q);
        const int k2 = (64 * c + 16 * seg + 4 * q) >> 1;
        sW[(k2 + 0) * STR2 + ol] = packh2(v.x, v.y);
        sW[(k2 + 1) * STR2 + ol] = packh2(v.z, v.w);
      }
    }
  }
  // ---- stage packed H2T slice: row j = t&7, k-chunk c = t>>3 (8 floats) ----
  {
    const int j = t & 7, c = t >> 3;
    const float* src = g_H2T + (size_t)(m0 + j) * 256 + 8 * c;
    float4 f0 = *(const float4*)(src);
    float4 f1 = *(const float4*)(src + 4);
    sH[(4 * c + 0) * 9 + j] = packh2(f0.x, f0.y);
    sH[(4 * c + 1) * 9 + j] = packh2(f0.z, f0.w);
    sH[(4 * c + 2) * 9 + j] = packh2(f1.x, f1.y);
    sH[(4 * c + 3) * 9 + j] = packh2(f1.z, f1.w);
  }
  __syncthreads();
  // ---- wave-split-K FMA phase: p = 4*tp+i, m = 2*tm+j ----
  const int w = t >> 6, lane = t & 63;
  const int tp = lane >> 2, tm = lane & 3;
  float acc[4][2] = {};
  const int kb2 = w * 32;
#pragma unroll 4
  for (int kk = 0; kk < 32; kk++) {
    const int k2 = kb2 + kk;
    uint4 ap = *(const uint4*)&sW[k2 * STR2 + 4 * tp];
    uint2 bp = *(const uint2*)&sH[k2 * 9 + 2 * tm];
    float2 a0 = __half22float2(*(__half2*)&ap.x);
    float2 a1 = __half22float2(*(__half2*)&ap.y);
    float2 a2 = __half22float2(*(__half2*)&ap.z);
    float2 a3 = __half22float2(*(__half2*)&ap.w);
    float2 b0 = __half22float2(*(__half2*)&bp.x);
    float2 b1v = __half22float2(*(__half2*)&bp.y);
    float ae[4] = {a0.x, a1.x, a2.x, a3.x};
    float ao[4] = {a0.y, a1.y, a2.y, a3.y};
#pragma unroll
    for (int i = 0; i < 4; i++) {
      acc[i][0] = fmaf(ae[i], b0.x, acc[i][0]);
      acc[i][0] = fmaf(ao[i], b0.y, acc[i][0]);
      acc[i][1] = fmaf(ae[i], b1v.x, acc[i][1]);
      acc[i][1] = fmaf(ao[i], b1v.y, acc[i][1]);
    }
  }
  __syncthreads();
  if (w > 0) {
#pragma unroll
    for (int i = 0; i < 4; i++) {
      red[((w - 1) * 64 + lane) * 8 + 2 * i + 0] = acc[i][0];
      red[((w - 1) * 64 + lane) * 8 + 2 * i + 1] = acc[i][1];
    }
  }
  __syncthreads();
  if (w == 0) {
#pragma unroll
    for (int v = 0; v < 3; v++) {
#pragma unroll
      for (int i = 0; i < 4; i++) {
        acc[i][0] += red[(v * 64 + lane) * 8 + 2 * i + 0];
        acc[i][1] += red[(v * 64 + lane) * 8 + 2 * i + 1];
      }
    }
#pragma unroll
    for (int i = 0; i < 4; i++) {
      const int p = 4 * tp + i;
      const int bi = (p < 63) ? (2 * p + 1) : 1;
      const float bias = b3[bi];
      raws[p * 9 + 2 * tm + 0] = acc[i][0] + bias;
      raws[p * 9 + 2 * tm + 1] = acc[i][1] + bias;
    }
  }
  __syncthreads();
  // ---- parallel processing: groups 0..7 (waves 0-1) -> 8 columns ----
  if (t < 128) {
    const int c = t >> 4, kl = t & 15;
    float wv = raws[kl * 9 + c];
    float hv = raws[(16 + kl) * 9 + c];
    float dvr = raws[(32 + kl) * 9 + c];
    float lamv = raws[(47 + kl) * 9 + c];
    process16(wv, hv, dvr, lamv, kl, g_table + (size_t)(m0 + c) * REC);
  } else if (blockIdx.x == 0 && (t >> 4) == 8) {
    // dim-0 constant knots from b3 even rows (concurrent with the above)
    const int kl = t & 15;
    float wv = b3[2 * kl];
    float hv = b3[2 * (16 + kl)];
    float dvr = b3[2 * (32 + kl)];
    float lamv = b3[2 * (47 + kl)];
    process16(wv, hv, dvr, lamv, kl, g_knots0);
  }
}

// ---------------- Main flow kernel: 4 steps per sample (unchanged)
__global__ __launch_bounds__(256) void k_main(const float* __restrict__ x,
                                              float* __restrict__ out) {
  __shared__ __attribute__((aligned(16))) float kn0[REC];
  for (int j = threadIdx.x; j < REC; j += 256) kn0[j] = g_knots0[j];
  __syncthreads();
  float kf0[16];
  {
    uint4 q0 = *(const uint4*)(kn0);
    uint4 q1 = *(const uint4*)(kn0 + 4);
    unpack8(q0, kf0);
    unpack8(q1, kf0 + 8);
  }
  const int i = blockIdx.x * 256 + threadIdx.x;
  const float2 xv = ((const float2*)x)[i];
  float z0 = xv.x, z1 = xv.y;
  ((float2*)out)[i] = xv;  // step 0 = input
  for (int t = 0; t < 4; t++) {
    float tt = (z0 - U_LO) * INV_DELTA;
    int i0 = (int)floorf(tt);
    i0 = min(max(i0, 0), M_GRID - 2);
    float f = fminf(fmaxf(tt - (float)i0, 0.0f), 1.0f);
    const float* r0 = g_table + (size_t)i0 * REC;
    float kf[16];
    {
      uint4 q0 = *(const uint4*)(r0);
      uint4 q1 = *(const uint4*)(r0 + 4);
      unpack8(q0, kf);
      unpack8(q1, kf + 8);
    }
    float xc1 = fminf(fmaxf(z1, -5.0f), 5.0f);
    int k1 = 0;
#pragma unroll
    for (int j = 1; j < 16; j++) k1 += (xc1 >= kf[j]) ? 1 : 0;
    const float* c0 = r0 + 8 + 4 * k1;
    uint4 A = *(const uint4*)c0;
    uint4 B = *(const uint4*)(c0 + REC);
    float2 Ay = __half22float2(*(__half2*)&A.x);
    float2 Ad = __half22float2(*(__half2*)&A.y);
    float2 Al = __half22float2(*(__half2*)&A.z);
    float2 Ax = __half22float2(*(__half2*)&A.w);
    float2 By = __half22float2(*(__half2*)&B.x);
    float2 Bd = __half22float2(*(__half2*)&B.y);
    float2 Bl = __half22float2(*(__half2*)&B.z);
    float2 Bx = __half22float2(*(__half2*)&B.w);
    float yk  = fmaf(f, By.x - Ay.x, Ay.x);
    float yk1 = fmaf(f, By.y - Ay.y, Ay.y);
    float dk  = fmaf(f, Bd.x - Ad.x, Ad.x);
    float dk1 = fmaf(f, Bd.y - Ad.y, Ad.y);
    float lam = fmaf(f, Bl.x - Al.x, Al.x);
    float xk  = fmaf(f, Bl.y - Al.y, Al.y);
    float xk1 = fmaf(f, Bx.x - Ax.x, Ax.x);
    float z1n = spline_eval(z1, xk, xk1, yk, yk1, dk, dk1, lam);
    float xc0 = fminf(fmaxf(z0, -5.0f), 5.0f);
    int k0 = 0;
#pragma unroll
    for (int j = 1; j < 16; j++) k0 += (xc0 >= kf0[j]) ? 1 : 0;
    uint4 C = *(const uint4*)&kn0[8 + 4 * k0];
    float2 Cy = __half22float2(*(__half2*)&C.x);
    float2 Cd = __half22float2(*(__half2*)&C.y);
    float2 Cl = __half22float2(*(__half2*)&C.z);
    float2 Cx = __half22float2(*(__half2*)&C.w);
    float z0n = spline_eval(z0, Cl.y, Cx.x, Cy.x, Cy.y, Cd.x, Cd.y, Cl.x);
    z0 = z0n; z1 = z1n;
    ((float2*)(out + (size_t)(t + 1) * (N_SAMPLES * 2)))[i] = make_float2(z0, z1);
  }
}

extern "C" void kernel_launch(void* const* d_in, const int* in_sizes, int n_in,
                              void* d_out, int out_size, void* d_ws, size_t ws_size,
                              hipStream_t stream) {
  const float* x  = (const float*)d_in[0];
  const float* W1 = (const float*)d_in[1];
  const float* b1 = (const float*)d_in[2];
  const float* W2 = (const float*)d_in[3];
  const float* b2 = (const float*)d_in[4];
  const float* W3 = (const float*)d_in[5];
  const float* b3 = (const float*)d_in[6];
  float* out = (float*)d_out;
  hipLaunchKernelGGL(k_gemm2, dim3(M_GRID / 32, 4), dim3(256), 0, stream, W1, b1, W2, b2);
  hipLaunchKernelGGL(k_gemm3proc, dim3(M_GRID / MT3), dim3(256), 0, stream, W3, b3);
  hipLaunchKernelGGL(k_main, dim3(N_SAMPLES / 256), dim3(256), 0, stream, x, out);
}